// Round 12
// baseline (2585.541 us; speedup 1.0000x reference)
//
#include <hip/hip_runtime.h>
#include <math.h>

// ---------------- problem dims (fixed by setup_inputs) ----------------
#define T_FRAMES 10
#define C_FEAT   64
#define IMG_H    480
#define IMG_W    640
#define P_PIX    (IMG_H*IMG_W)     // 307200
#define MAP_H    250
#define MAP_W    250
#define M_CELLS  (MAP_H*MAP_W)     // 62500
#define D_MEM    256
#define N_CLS    20
#define NPAD     62528             // M_CELLS padded to 64
#define GBLK2    768               // persistent GRU grid: 3 blocks/CU, provably resident

// padded channels-last plane geometry for bf16 activations: interior origin (3,3)
#define PW  272
#define PH  262
#define PP  (PH*PW)                // 71264 px per padded plane

typedef __attribute__((ext_vector_type(8))) short s16x8;   // 8 bf16 (4 VGPR)
typedef __attribute__((ext_vector_type(4))) float f32x4;   // MFMA acc

__device__ __forceinline__ unsigned short f2bf(float f) {
    unsigned int u = __float_as_uint(f);
    u += 0x7fffu + ((u >> 16) & 1u);      // RNE
    return (unsigned short)(u >> 16);
}
__device__ __forceinline__ float bf2f(unsigned short b) {
    return __uint_as_float(((unsigned int)b) << 16);
}
__device__ __forceinline__ uint4 pack8u(float4 a, float4 b) {
    uint4 r;
    r.x = (unsigned int)f2bf(a.x) | ((unsigned int)f2bf(a.y) << 16);
    r.y = (unsigned int)f2bf(a.z) | ((unsigned int)f2bf(a.w) << 16);
    r.z = (unsigned int)f2bf(b.x) | ((unsigned int)f2bf(b.y) << 16);
    r.w = (unsigned int)f2bf(b.z) | ((unsigned int)f2bf(b.w) << 16);
    return r;
}

// ===================== scan phase (frame-parallel) =====================
// packed[t][m] = max over frame-t inlier pixels of (height_bits<<32 | pixel).
// u64 atomicMax = lexicographic (max height, then max pixel) == reference tie rule.

__global__ __launch_bounds__(256) void k_scatter_all(const int2* __restrict__ proj,
                                                     const int* __restrict__ mask,
                                                     const float* __restrict__ heights,
                                                     unsigned long long* __restrict__ packed,
                                                     int* __restrict__ ps) {
    int t = blockIdx.y;
    int p = blockIdx.x * 256 + threadIdx.x;           // grid.x*256 == P_PIX exactly
    size_t gp = (size_t)t * P_PIX + p;
    ps[gp] = -1;                                      // init inverse map in-kernel
    if (mask[gp]) return;                             // outlier: never wins
    int2 pr = proj[gp];
    int idx = MAP_W * pr.y + pr.x;
    float mh = heights[gp] + 1000.0f;                 // > 0 -> uint order == float order
    unsigned long long pk = ((unsigned long long)__float_as_uint(mh) << 32)
                            | (unsigned int)p;
    atomicMax(packed + (size_t)t * M_CELLS + idx, pk);
}

// k_sched: per cell, walk the 10 frame-maxima in registers; emit per-frame
// updlists/slots/winner-pixel map, plus final hmap/observed direct to d_out.

__global__ __launch_bounds__(256) void k_sched(const unsigned long long* __restrict__ packed,
                                               int* __restrict__ updlist,   // [T][NPAD]
                                               int* __restrict__ ps,        // [T][P_PIX]
                                               int* __restrict__ count,     // [T]
                                               float* __restrict__ out) {
    int m = blockIdx.x * 256 + threadIdx.x;
    if (m >= M_CELLS) return;
    unsigned int pv = 0;                               // == 0.0f (hmap init)
    bool any = false;
    #pragma unroll
    for (int t = 0; t < T_FRAMES; ++t) {
        unsigned long long pk = packed[(size_t)t * M_CELLS + m];
        unsigned int hb = (unsigned int)(pk >> 32);
        if (hb > pv) {                                 // strict: matches new_hmap > hmap
            int slot = atomicAdd(count + t, 1);
            updlist[t * NPAD + slot] = m;
            ps[(size_t)t * P_PIX + (pk & 0xffffffffu)] = slot;
            pv = hb;
            any = true;
        }
    }
    out[(size_t)N_CLS * M_CELLS + m] = any ? 1.0f : 0.0f;
    out[(size_t)N_CLS * M_CELLS + M_CELLS + m] = __uint_as_float(pv);
}

// k_gx_all: ALL frames' winner-pixel feature gather, pixel-order (coalesced).

__global__ __launch_bounds__(256) void k_gx_all(const float* __restrict__ feat_all,
                                                const int* __restrict__ ps,
                                                short* __restrict__ Agx) {
    int t = blockIdx.y;
    int p = blockIdx.x * 256 + threadIdx.x;
    int i = ps[(size_t)t * P_PIX + p];
    if (i < 0) return;
    const float* feat = feat_all + (size_t)t * C_FEAT * P_PIX;
    short* dst = Agx + ((size_t)t * NPAD + i) * 64;
    #pragma unroll
    for (int c8 = 0; c8 < 8; ++c8) {
        unsigned int pk[4];
        #pragma unroll
        for (int q = 0; q < 4; ++q) {
            float f0 = feat[(size_t)(c8 * 8 + 2 * q)     * P_PIX + p];
            float f1 = feat[(size_t)(c8 * 8 + 2 * q + 1) * P_PIX + p];
            pk[q] = (unsigned int)f2bf(f0) | ((unsigned int)f2bf(f1) << 16);
        }
        *(uint4*)(dst + c8 * 8) = make_uint4(pk[0], pk[1], pk[2], pk[3]);
    }
}

// ===================== weight pre-transforms (one dispatch) =====================

__device__ __forceinline__ void wprep_gru_item(int idx,
        const float* __restrict__ w_ih, const float* __restrict__ w_hh,
        short* __restrict__ wq) {
    int gp = idx & 1023, k8 = idx >> 10;
    int tau = gp >> 8, gl = gp & 255;
    unsigned int pk[4];
    #pragma unroll
    for (int q = 0; q < 4; ++q) {
        unsigned int h2[2];
        #pragma unroll
        for (int e = 0; e < 2; ++e) {
            int k = k8 * 8 + q * 2 + e;
            float v = 0.f;
            if (tau == 0)      v = (k < 64) ? w_ih[(size_t)gl * 64 + k]
                                            : w_hh[(size_t)gl * 256 + (k - 64)];
            else if (tau == 1) v = (k < 64) ? w_ih[(size_t)(256 + gl) * 64 + k]
                                            : w_hh[(size_t)(256 + gl) * 256 + (k - 64)];
            else if (tau == 2) v = (k < 64) ? w_ih[(size_t)(512 + gl) * 64 + k] : 0.f;
            else               v = (k < 64) ? 0.f
                                            : w_hh[(size_t)(512 + gl) * 256 + (k - 64)];
            h2[e] = f2bf(v);
        }
        pk[q] = h2[0] | (h2[1] << 16);
    }
    *(uint4*)(wq + (size_t)idx * 8) = make_uint4(pk[0], pk[1], pk[2], pk[3]);
}

__device__ __forceinline__ void wprep_conv_item(int idx, const float* __restrict__ w,
        short* __restrict__ wm, int OC, int CIN, int OCP, int CINP, int KS) {
    int oc  = idx % OCP;
    int t2  = idx / OCP;
    int ci8 = t2 % (CINP / 8);
    int tap = t2 / (CINP / 8);
    unsigned int pk[4];
    #pragma unroll
    for (int q = 0; q < 4; ++q) {
        unsigned int h[2];
        #pragma unroll
        for (int e = 0; e < 2; ++e) {
            int ci = ci8 * 8 + 2*q + e;
            float v = (oc < OC && ci < CIN)
                ? w[((size_t)oc * CIN + ci) * KS * KS + tap] : 0.f;
            h[e] = f2bf(v);
        }
        pk[q] = h[0] | (h[1] << 16);
    }
    *(uint4*)(wm + (size_t)idx * 8) = make_uint4(pk[0], pk[1], pk[2], pk[3]);
}

__global__ __launch_bounds__(256) void k_wprep_all(
        const float* __restrict__ w_ih, const float* __restrict__ w_hh,
        short* __restrict__ wq,
        const float* __restrict__ c1_w, short* __restrict__ wm1,
        const float* __restrict__ c2_w, short* __restrict__ wm2,
        const float* __restrict__ c3_w, short* __restrict__ wm3,
        const float* __restrict__ c4_w, short* __restrict__ wm4) {
    int idx = blockIdx.x * 256 + threadIdx.x;
    switch (blockIdx.y) {
    case 0: if (idx < 40 * 1024)    wprep_gru_item(idx, w_ih, w_hh, wq); break;
    case 1: if (idx < 49*32*128)    wprep_conv_item(idx, c1_w, wm1, 128, 256, 128, 256, 7); break;
    case 2: if (idx < 9*16*64)      wprep_conv_item(idx, c2_w, wm2,  64, 128,  64, 128, 3); break;
    case 3: if (idx < 9*8*64)       wprep_conv_item(idx, c3_w, wm3,  48,  64,  64,  64, 3); break;
    default: if (idx < 9*8*64)      wprep_conv_item(idx, c4_w, wm4,  48,  48,  64,  64, 3); break;
    }
}

// ===================== persistent GRU chain, v4 structure =====================
// ONE launch, GBLK2=768 blocks (3/CU guaranteed: launch_bounds(256,3) caps VGPR
// at 170, LDS 3x40KB <= 160KB). Per frame: sweep 64-cell groups (stride GBLK2*64)
// with the v4 body (B staged once in swizzled LDS, A-reuse 4x, zero-tau skip,
// ck loop split so all accumulator indices are compile-time). Grid barrier with
// release/acquire threadfences between frames (pattern validated R9).

__global__ __launch_bounds__(256, 3) void k_gruchain2(
        const short* __restrict__ Agx,
        const short* __restrict__ wq,
        const float* __restrict__ b_ih, const float* __restrict__ b_hh,
        const int* __restrict__ updlist, const int* __restrict__ count,
        float* __restrict__ state, int* __restrict__ bar) {
    __shared__ alignas(16) char B[64 * 640];    // [cell][320 bf16], swizzled
    __shared__ int ml[64];
    const int tid = threadIdx.x;
    const int w = tid >> 6, l = tid & 63, u = l & 15, s = l >> 4;

    for (int t = 0; t < T_FRAMES; ++t) {
        const int n = count[t];
        const short* Agx_t = Agx + (size_t)t * NPAD * 64;
        const int* upd = updlist + t * NPAD;

        for (int base = blockIdx.x * 64; base < n; base += GBLK2 * 64) {
            __syncthreads();                     // protect B/ml reuse across sweeps
            if (tid < 64) {
                int i = base + tid; if (i > n - 1) i = n - 1;   // tail clamp
                ml[tid] = upd[i];
            }
            __syncthreads();

            // stage x-part (k 0..63) from Agx: 512 x 16B
            for (int e = tid; e < 512; e += 256) {
                int cell = e >> 3, kc = e & 7;
                uint4 v = *(const uint4*)(Agx_t + ((size_t)(base + cell)) * 64 + kc * 8);
                int dst = (cell * 640 + kc * 16) ^ ((cell & 7) << 4);
                *(uint4*)(B + dst) = v;
            }
            // stage h-part (k 64..319) from fp32 state, convert: 2048 x 16B
            for (int e = tid; e < 2048; e += 256) {
                int cell = e >> 5, kc = e & 31;
                const float* sp = state + (size_t)ml[cell] * D_MEM + kc * 8;
                float4 v0 = *(const float4*)sp;
                float4 v1 = *(const float4*)(sp + 4);
                int dst = (cell * 640 + 128 + kc * 16) ^ ((cell & 7) << 4);
                *(uint4*)(B + dst) = pack8u(v0, v1);
            }
            __syncthreads();

            #pragma unroll 1
            for (int g16 = w; g16 < 16; g16 += 4) {
                f32x4 aR[4], aZ[4], aI[4], aH[4];
                #pragma unroll
                for (int cf = 0; cf < 4; ++cf) {
                    aR[cf] = (f32x4){0.f,0.f,0.f,0.f}; aZ[cf] = (f32x4){0.f,0.f,0.f,0.f};
                    aI[cf] = (f32x4){0.f,0.f,0.f,0.f}; aH[cf] = (f32x4){0.f,0.f,0.f,0.f};
                }

                // ck 0-1: x-part (r, z, inn) -- compile-time accumulator targets
                #pragma unroll
                for (int ck = 0; ck < 2; ++ck) {
                    s16x8 b[4];
                    #pragma unroll
                    for (int cf = 0; cf < 4; ++cf) {
                        int cell = 16 * cf + u;
                        int byte = (cell * 640 + ck * 64 + s * 16) ^ ((cell & 7) << 4);
                        b[cf] = *(const s16x8*)(B + byte);
                    }
                    const short* wr = wq + ((size_t)(ck * 4 + s) * 1024 + g16 * 16 + u) * 8;
                    s16x8 ar = *(const s16x8*)(wr);
                    s16x8 az = *(const s16x8*)(wr + 256 * 8);
                    s16x8 an = *(const s16x8*)(wr + 512 * 8);
                    #pragma unroll
                    for (int cf = 0; cf < 4; ++cf) {
                        aR[cf] = __builtin_amdgcn_mfma_f32_16x16x32_bf16(ar, b[cf], aR[cf], 0, 0, 0);
                        aZ[cf] = __builtin_amdgcn_mfma_f32_16x16x32_bf16(az, b[cf], aZ[cf], 0, 0, 0);
                        aI[cf] = __builtin_amdgcn_mfma_f32_16x16x32_bf16(an, b[cf], aI[cf], 0, 0, 0);
                    }
                }
                // ck 2-9: h-part (r, z, hn) -- bounded unroll to contain VGPRs
                #pragma unroll 2
                for (int ck = 2; ck < 10; ++ck) {
                    s16x8 b[4];
                    #pragma unroll
                    for (int cf = 0; cf < 4; ++cf) {
                        int cell = 16 * cf + u;
                        int byte = (cell * 640 + ck * 64 + s * 16) ^ ((cell & 7) << 4);
                        b[cf] = *(const s16x8*)(B + byte);
                    }
                    const short* wr = wq + ((size_t)(ck * 4 + s) * 1024 + g16 * 16 + u) * 8;
                    s16x8 ar = *(const s16x8*)(wr);
                    s16x8 az = *(const s16x8*)(wr + 256 * 8);
                    s16x8 an = *(const s16x8*)(wr + 768 * 8);
                    #pragma unroll
                    for (int cf = 0; cf < 4; ++cf) {
                        aR[cf] = __builtin_amdgcn_mfma_f32_16x16x32_bf16(ar, b[cf], aR[cf], 0, 0, 0);
                        aZ[cf] = __builtin_amdgcn_mfma_f32_16x16x32_bf16(az, b[cf], aZ[cf], 0, 0, 0);
                        aH[cf] = __builtin_amdgcn_mfma_f32_16x16x32_bf16(an, b[cf], aH[cf], 0, 0, 0);
                    }
                }

                // epilogue: d = g16*16 + 4s + r, cells 16cf+u
                const int d0 = g16 * 16 + 4 * s;
                #pragma unroll
                for (int cf = 0; cf < 4; ++cf) {
                    if (base + 16 * cf + u < n) {
                        float* sp = state + (size_t)ml[16 * cf + u] * D_MEM;
                        float4 h = *(const float4*)(sp + d0);
                        float hv[4] = {h.x, h.y, h.z, h.w};
                        float ov[4];
                        #pragma unroll
                        for (int r = 0; r < 4; ++r) {
                            int d = d0 + r;
                            float rr = aR[cf][r] + b_ih[d]       + b_hh[d];
                            float zz = aZ[cf][r] + b_ih[256 + d] + b_hh[256 + d];
                            float ii = aI[cf][r] + b_ih[512 + d];
                            float hh = aH[cf][r] + b_hh[512 + d];
                            float rv = 1.f / (1.f + expf(-rr));
                            float zv = 1.f / (1.f + expf(-zz));
                            float nv = tanhf(ii + rv * hh);
                            ov[r] = (1.f - zv) * nv + zv * hv[r];
                        }
                        *(float4*)(sp + d0) = make_float4(ov[0], ov[1], ov[2], ov[3]);
                    }
                }
            }
        }

        // ---- grid barrier between frames ----
        __syncthreads();
        __threadfence();                         // release: drain state writes
        if (tid == 0) {
            atomicAdd(bar + t, 1);
            while (atomicAdd(bar + t, 0) < GBLK2) __builtin_amdgcn_s_sleep(8);
        }
        __syncthreads();
        __threadfence();                         // acquire
    }
}

// ===================== MFMA implicit-GEMM conv, fully fused BN =====================
// TLY = output rows per wave (block = 16 x 4*TLY px). F32IN: read fp32 state
// directly (convert in staging). NORM: apply prev-layer relu(bn(x)) during
// staging; interior mask keeps pads 0. STATS: BN sums from f32 accumulators.

template<int CINP, int KS, int TLY, bool NORM, bool STATS, bool F32OUT, bool F32IN>
__global__ __launch_bounds__(256) void k_cmfma(const void* __restrict__ in,
                                               const short* __restrict__ wm,
                                               int OCT,
                                               void* __restrict__ out,
                                               int OCS,
                                               const float* __restrict__ sums_in,
                                               const float* __restrict__ sums2_in,
                                               const float* __restrict__ g_in,
                                               const float* __restrict__ b_in,
                                               int OCPREV,
                                               float* __restrict__ sums_out,
                                               float* __restrict__ sums2_out) {
    constexpr int PAD = KS / 2;
    constexpr int BH  = 4 * TLY;
    constexpr int PTW_X = 16 + KS - 1;
    constexpr int PTW_Y = BH + KS - 1;
    __shared__ alignas(16) char patch[PTW_Y * PTW_X * 64];
    __shared__ float scl[NORM ? CINP : 1], shf[NORM ? CINP : 1];
    __shared__ float st1[4][64], st2[4][64];

    const int tid = threadIdx.x;
    const int w   = tid >> 6;
    const int l   = tid & 63;
    const int u   = l & 15;
    const int s   = l >> 4;

    const int x0  = 3 + 16 * blockIdx.x;
    const int y0  = 3 + BH * blockIdx.y;
    const int oc0 = 64 * blockIdx.z;

    if constexpr (NORM) {
        for (int c = tid; c < CINP; c += 256) {
            float sc = 0.f, sh = 0.f;
            if (c < OCPREV) {
                float mu  = sums_in[c] * (1.f / M_CELLS);
                float var = sums2_in[c] * (1.f / M_CELLS) - mu * mu;
                float rs  = rsqrtf(var + 1e-5f);
                sc = g_in[c] * rs;
                sh = b_in[c] - mu * rs * g_in[c];
            }
            scl[c] = sc; shf[c] = sh;
        }
    }

    f32x4 acc[TLY][4];   // [yy][o]
    #pragma unroll
    for (int yy = 0; yy < TLY; ++yy)
        #pragma unroll
        for (int o = 0; o < 4; ++o)
            acc[yy][o] = (f32x4){0.f, 0.f, 0.f, 0.f};

    for (int ci0 = 0; ci0 < CINP; ci0 += 32) {
        __syncthreads();
        for (int e = tid; e < PTW_Y * PTW_X * 4; e += 256) {
            int c8 = e & 3;
            int pp = e >> 2;
            int px = pp % PTW_X, py = pp / PTW_X;
            int gy = y0 - PAD + py, gx = x0 - PAD + px;
            bool inb = (gy >= 3) && (gy < 253) && (gx >= 3) && (gx < 253);
            uint4 v = make_uint4(0, 0, 0, 0);
            if constexpr (F32IN) {
                if (inb) {
                    int m = (gy - 3) * MAP_W + (gx - 3);
                    const float* sp = (const float*)in + (size_t)m * 256 + ci0 + c8 * 8;
                    float4 v0 = *(const float4*)sp;
                    float4 v1 = *(const float4*)(sp + 4);
                    v = pack8u(v0, v1);
                }
            } else {
                v = *(const uint4*)((const short*)in + ((size_t)gy * PW + gx) * CINP
                                    + ci0 + c8 * 8);
                if constexpr (NORM) {
                    int cb = ci0 + c8 * 8;
                    unsigned int uu[4] = {v.x, v.y, v.z, v.w};
                    unsigned int ro[4];
                    #pragma unroll
                    for (int q = 0; q < 4; ++q) {
                        float f0 = bf2f((unsigned short)(uu[q] & 0xffffu));
                        float f1 = bf2f((unsigned short)(uu[q] >> 16));
                        f0 = fmaxf(fmaf(f0, scl[cb + 2*q],     shf[cb + 2*q]),     0.f);
                        f1 = fmaxf(fmaf(f1, scl[cb + 2*q + 1], shf[cb + 2*q + 1]), 0.f);
                        ro[q] = (unsigned int)f2bf(f0) | ((unsigned int)f2bf(f1) << 16);
                    }
                    v = make_uint4(ro[0], ro[1], ro[2], ro[3]);
                }
                if (!inb) v = make_uint4(0, 0, 0, 0);
            }
            int lb = (((py * PTW_X + px) * 64) + c8 * 16) ^ ((px & 3) << 4);
            *(uint4*)(patch + lb) = v;
        }
        __syncthreads();

        const short* wb = wm + ((size_t)(ci0 / 8 + s) * OCT + oc0 + u) * 8;

        for (int ky = 0; ky < KS; ++ky) {
            for (int kx = 0; kx < KS; ++kx) {
                const int tap = ky * KS + kx;
                const short* wt = wb + (size_t)tap * (CINP / 8) * OCT * 8;
                s16x8 a[4];
                #pragma unroll
                for (int o = 0; o < 4; ++o)
                    a[o] = *(const s16x8*)(wt + o * 16 * 8);
                const int px = kx + u;
                const int lb0 = ((px * 64) + s * 16) ^ ((px & 3) << 4);
                #pragma unroll
                for (int yy = 0; yy < TLY; ++yy) {
                    int py = TLY * w + yy + ky;
                    s16x8 b = *(const s16x8*)(patch + py * PTW_X * 64 + lb0);
                    #pragma unroll
                    for (int o = 0; o < 4; ++o)
                        acc[yy][o] = __builtin_amdgcn_mfma_f32_16x16x32_bf16(
                            a[o], b, acc[yy][o], 0, 0, 0);
                }
            }
        }
    }

    const int gx = x0 + u;
    const bool colok = (gx < 253);

    if constexpr (STATS) {
        float s1[16], s2[16];
        #pragma unroll
        for (int e = 0; e < 16; ++e) { s1[e] = 0.f; s2[e] = 0.f; }
        #pragma unroll
        for (int yy = 0; yy < TLY; ++yy) {
            int gy = y0 + TLY * w + yy;
            if (colok && gy < 253) {
                #pragma unroll
                for (int o = 0; o < 4; ++o)
                    #pragma unroll
                    for (int r = 0; r < 4; ++r) {
                        float v = acc[yy][o][r];
                        s1[o*4+r] += v; s2[o*4+r] += v * v;
                    }
            }
        }
        #pragma unroll
        for (int off = 1; off < 16; off <<= 1)
            #pragma unroll
            for (int e = 0; e < 16; ++e) {
                s1[e] += __shfl_xor(s1[e], off, 64);
                s2[e] += __shfl_xor(s2[e], off, 64);
            }
        if (u == 0) {
            #pragma unroll
            for (int e = 0; e < 16; ++e) {
                int ch = (e >> 2) * 16 + s * 4 + (e & 3);
                st1[w][ch] = s1[e]; st2[w][ch] = s2[e];
            }
        }
        __syncthreads();
        if (tid < 64) {
            float a1 = st1[0][tid] + st1[1][tid] + st1[2][tid] + st1[3][tid];
            float a2 = st2[0][tid] + st2[1][tid] + st2[2][tid] + st2[3][tid];
            atomicAdd(sums_out  + oc0 + tid, a1);
            atomicAdd(sums2_out + oc0 + tid, a2);
        }
    }

    if (!colok) return;
    #pragma unroll
    for (int yy = 0; yy < TLY; ++yy) {
        int gy = y0 + TLY * w + yy;
        if (gy >= 253) continue;
        #pragma unroll
        for (int o = 0; o < 4; ++o) {
            int oc = oc0 + o * 16 + s * 4;
            if constexpr (F32OUT) {
                int m = (gy - 3) * MAP_W + (gx - 3);
                float* op = (float*)out + (size_t)m * 48 + oc;
                #pragma unroll
                for (int r = 0; r < 4; ++r)
                    if (oc + r < 48) op[r] = acc[yy][o][r];
            } else {
                short* op = (short*)out + ((size_t)gy * PW + gx) * OCS + oc;
                unsigned int w0 = f2bf(acc[yy][o][0]) | ((unsigned int)f2bf(acc[yy][o][1]) << 16);
                unsigned int w1 = f2bf(acc[yy][o][2]) | ((unsigned int)f2bf(acc[yy][o][3]) << 16);
                *(uint2*)op = make_uint2(w0, w1);
            }
        }
    }
}

// ===================== conv5 (1x1) + bias, fused bn4(from sums)+relu =====================

__global__ __launch_bounds__(256) void k_conv5(const float* __restrict__ x4, // [M][48]
                                               const float* __restrict__ w,
                                               const float* __restrict__ bias,
                                               const float* __restrict__ sums4,
                                               const float* __restrict__ sums24,
                                               const float* __restrict__ g4,
                                               const float* __restrict__ b4,
                                               float* __restrict__ sem) {
    __shared__ float wl[N_CLS * 48];
    __shared__ float scl[48], shf[48], bl[N_CLS];
    int tid = threadIdx.x;
    for (int e = tid; e < N_CLS * 48; e += 256) wl[e] = w[e];
    if (tid < 48) {
        float mu  = sums4[tid] * (1.f / M_CELLS);
        float var = sums24[tid] * (1.f / M_CELLS) - mu * mu;
        float rs  = rsqrtf(var + 1e-5f);
        scl[tid] = g4[tid] * rs;
        shf[tid] = b4[tid] - mu * rs * g4[tid];
    }
    if (tid < N_CLS) bl[tid] = bias[tid];
    __syncthreads();
    int p = blockIdx.x * 256 + tid;
    if (p >= M_CELLS) return;
    float inr[48];
    const float4* xp = (const float4*)(x4 + (size_t)p * 48);
    #pragma unroll
    for (int q = 0; q < 12; ++q) {
        float4 v = xp[q];
        inr[4*q+0] = v.x; inr[4*q+1] = v.y; inr[4*q+2] = v.z; inr[4*q+3] = v.w;
    }
    #pragma unroll
    for (int c = 0; c < 48; ++c)
        inr[c] = fmaxf(fmaf(inr[c], scl[c], shf[c]), 0.f);
    #pragma unroll
    for (int o = 0; o < N_CLS; ++o) {
        float a = bl[o];
        #pragma unroll
        for (int c = 0; c < 48; ++c) a = fmaf(inr[c], wl[o * 48 + c], a);
        sem[(size_t)o * M_CELLS + p] = a;
    }
}

// ===================== host launcher =====================

extern "C" void kernel_launch(void* const* d_in, const int* in_sizes, int n_in,
                              void* d_out, int out_size, void* d_ws, size_t ws_size,
                              hipStream_t stream) {
    (void)in_sizes; (void)n_in; (void)out_size; (void)ws_size;

    const float* features = (const float*)d_in[0];
    const int*   proj     = (const int*)d_in[1];
    const int*   mask     = (const int*)d_in[2];
    const float* heights  = (const float*)d_in[3];
    const float* w_ih  = (const float*)d_in[6];
    const float* w_hh  = (const float*)d_in[7];
    const float* b_ih  = (const float*)d_in[8];
    const float* b_hh  = (const float*)d_in[9];
    const float* c1_w  = (const float*)d_in[10];
    const float* bn1_g = (const float*)d_in[11];
    const float* bn1_b = (const float*)d_in[12];
    const float* c2_w  = (const float*)d_in[13];
    const float* bn2_g = (const float*)d_in[14];
    const float* bn2_b = (const float*)d_in[15];
    const float* c3_w  = (const float*)d_in[16];
    const float* bn3_g = (const float*)d_in[17];
    const float* bn3_b = (const float*)d_in[18];
    const float* c4_w  = (const float*)d_in[19];
    const float* bn4_g = (const float*)d_in[20];
    const float* bn4_b = (const float*)d_in[21];
    const float* c5_w  = (const float*)d_in[22];
    const float* c5_b  = (const float*)d_in[23];

    // ---- workspace layout; [state|packed|count|sums|sums2|bar] one zero region ----
    char* ws = (char*)d_ws;
    float* state = (float*)(ws);                                   // 64.0 MB
    unsigned long long* packed = (unsigned long long*)(ws + 64000000); // 5.0 MB [T][M]
    int*   count   = (int*)(ws + 69000000);                        // 64 B [T]
    float* sums    = (float*)(ws + 69000064);                      // 512 f
    float* sums2   = (float*)(ws + 69002112);                      // 512 f
    int*   bar     = (int*)(ws + 69004160);                        // 64 B [T]
    int*   ps      = (int*)(ws + 70000000);                        // 12.3 MB [T][P]
    int*   updlist = (int*)(ws + 83000000);                        //  2.5 MB [T][NPAD]
    short* Agx     = (short*)(ws + 86000000);                      // 80.0 MB [T][NPAD][64]
    short* wq      = (short*)(ws + 167000000);                     // 0.66 MB
    short* wm1     = (short*)(ws + 168000000);                     // 3.2 MB
    short* wm2     = (short*)(ws + 171300000);
    short* wm3     = (short*)(ws + 171500000);
    short* wm4     = (short*)(ws + 171600000);
    short* x1_cl   = (short*)(ws + 172000000);                     // 18.2 MB
    short* x2_cl   = (short*)(ws + 191000000);                     //  9.1 MB
    short* x3_cl   = (short*)(ws + 201000000);                     //  9.1 MB
    float* x4      = (float*)(ws + 211000000);                     // 12.0 MB

    // one zero-memset: state + packed + count + sums + sums2 + bar
    hipMemsetAsync(ws, 0, 69004224, stream);

    // all weight pre-transforms in one dispatch
    k_wprep_all<<<dim3(784, 5), 256, 0, stream>>>(w_ih, w_hh, wq,
                                                  c1_w, wm1, c2_w, wm2,
                                                  c3_w, wm3, c4_w, wm4);

    const int PB = P_PIX / 256;                  // 1200
    const int MB = (M_CELLS + 255) / 256;        // 245

    // frame-parallel scan
    k_scatter_all<<<dim3(PB, T_FRAMES), 256, 0, stream>>>(
        (const int2*)proj, mask, heights, packed, ps);
    k_sched<<<MB, 256, 0, stream>>>(packed, updlist, ps, count, (float*)d_out);
    k_gx_all<<<dim3(PB, T_FRAMES), 256, 0, stream>>>(features, ps, Agx);

    // persistent GRU chain: ONE launch, grid barrier per frame (v4 structure)
    k_gruchain2<<<GBLK2, 256, 0, stream>>>(Agx, wq, b_ih, b_hh,
                                           updlist, count, state, bar);

    // conv1 7x7 256->128: TLY=4 (2 blocks/CU), fp32 state input, stats out
    k_cmfma<256, 7, 4, false, true, false, true><<<dim3(16, 16, 2), 256, 0, stream>>>(
        state, wm1, 128, x1_cl, 128,
        nullptr, nullptr, nullptr, nullptr, 0, sums + 0, sums2 + 0);

    // conv2 3x3 128->64 (bn1 from sums fused in; stats out)
    k_cmfma<128, 3, 4, true, true, false, false><<<dim3(16, 16, 1), 256, 0, stream>>>(
        x1_cl, wm2, 64, x2_cl, 64,
        sums + 0, sums2 + 0, bn1_g, bn1_b, 128, sums + 128, sums2 + 128);

    // conv3 3x3 64->48 (bn2 in; stats out)
    k_cmfma<64, 3, 4, true, true, false, false><<<dim3(16, 16, 1), 256, 0, stream>>>(
        x2_cl, wm3, 64, x3_cl, 64,
        sums + 128, sums2 + 128, bn2_g, bn2_b, 64, sums + 192, sums2 + 192);

    // conv4 3x3 48->48 (bn3 in; stats out) -> compact f32 [M][48]
    k_cmfma<64, 3, 4, true, true, true, false><<<dim3(16, 16, 1), 256, 0, stream>>>(
        x3_cl, wm4, 64, x4, 48,
        sums + 192, sums2 + 192, bn3_g, bn3_b, 48, sums + 256, sums2 + 256);

    // conv5 1x1 48->20 + bias (bn4 from sums fused) -> sem
    k_conv5<<<MB, 256, 0, stream>>>(x4, c5_w, c5_b,
                                    sums + 256, sums2 + 256, bn4_g, bn4_b,
                                    (float*)d_out);
}

// Round 13
// 1667.534 us; speedup vs baseline: 1.5505x; 1.5505x over previous
//
#include <hip/hip_runtime.h>
#include <math.h>

// ---------------- problem dims (fixed by setup_inputs) ----------------
#define T_FRAMES 10
#define C_FEAT   64
#define IMG_H    480
#define IMG_W    640
#define P_PIX    (IMG_H*IMG_W)     // 307200
#define MAP_H    250
#define MAP_W    250
#define M_CELLS  (MAP_H*MAP_W)     // 62500
#define D_MEM    256
#define N_CLS    20
#define NPAD     62528             // M_CELLS padded to 64

// padded channels-last plane geometry for bf16 activations: interior origin (3,3)
#define PW  272
#define PH  262
#define PP  (PH*PW)                // 71264 px per padded plane

typedef __attribute__((ext_vector_type(8))) short s16x8;   // 8 bf16 (4 VGPR)
typedef __attribute__((ext_vector_type(4))) float f32x4;   // MFMA acc

__device__ __forceinline__ unsigned short f2bf(float f) {
    unsigned int u = __float_as_uint(f);
    u += 0x7fffu + ((u >> 16) & 1u);      // RNE
    return (unsigned short)(u >> 16);
}
__device__ __forceinline__ float bf2f(unsigned short b) {
    return __uint_as_float(((unsigned int)b) << 16);
}
__device__ __forceinline__ uint4 pack8u(float4 a, float4 b) {
    uint4 r;
    r.x = (unsigned int)f2bf(a.x) | ((unsigned int)f2bf(a.y) << 16);
    r.y = (unsigned int)f2bf(a.z) | ((unsigned int)f2bf(a.w) << 16);
    r.z = (unsigned int)f2bf(b.x) | ((unsigned int)f2bf(b.y) << 16);
    r.w = (unsigned int)f2bf(b.z) | ((unsigned int)f2bf(b.w) << 16);
    return r;
}

// ===================== scan phase (frame-parallel) =====================
// packed[t][m] = max over frame-t inlier pixels of (height_bits<<32 | pixel).
// u64 atomicMax = lexicographic (max height, then max pixel) == reference tie rule.

__global__ __launch_bounds__(256) void k_scatter_all(const int2* __restrict__ proj,
                                                     const int* __restrict__ mask,
                                                     const float* __restrict__ heights,
                                                     unsigned long long* __restrict__ packed,
                                                     int* __restrict__ ps) {
    int t = blockIdx.y;
    int p = blockIdx.x * 256 + threadIdx.x;           // grid.x*256 == P_PIX exactly
    size_t gp = (size_t)t * P_PIX + p;
    ps[gp] = -1;                                      // init inverse map in-kernel
    if (mask[gp]) return;                             // outlier: never wins
    int2 pr = proj[gp];
    int idx = MAP_W * pr.y + pr.x;
    float mh = heights[gp] + 1000.0f;                 // > 0 -> uint order == float order
    unsigned long long pk = ((unsigned long long)__float_as_uint(mh) << 32)
                            | (unsigned int)p;
    atomicMax(packed + (size_t)t * M_CELLS + idx, pk);
}

// k_sched: per cell, walk the 10 frame-maxima in registers; emit the per-cell
// update-chain metadata (kcnt, cfr = frame of j-th update), winner-pixel -> cell
// map, update-count histogram, and final hmap/observed direct to d_out.

__global__ __launch_bounds__(256) void k_sched(const unsigned long long* __restrict__ packed,
                                               signed char* __restrict__ cfr,  // [M][10]
                                               int* __restrict__ kcnt,         // [M]
                                               int* __restrict__ ps,           // [T][P_PIX]
                                               int* __restrict__ hist,         // [16]
                                               float* __restrict__ out) {
    int m = blockIdx.x * 256 + threadIdx.x;
    if (m >= M_CELLS) return;
    unsigned int pv = 0;                               // == 0.0f (hmap init)
    int k = 0;
    #pragma unroll
    for (int t = 0; t < T_FRAMES; ++t) {
        unsigned long long pk = packed[(size_t)t * M_CELLS + m];
        unsigned int hb = (unsigned int)(pk >> 32);
        if (hb > pv) {                                 // strict: matches new_hmap > hmap
            cfr[m * 10 + k] = (signed char)t;
            ps[(size_t)t * P_PIX + (pk & 0xffffffffu)] = m;
            pv = hb;
            ++k;
        }
    }
    kcnt[m] = k;
    atomicAdd(hist + k, 1);
    out[(size_t)N_CLS * M_CELLS + m] = k > 0 ? 1.0f : 0.0f;
    out[(size_t)N_CLS * M_CELLS + M_CELLS + m] = __uint_as_float(pv);
}

// k_prefix: bin offsets for descending-k counting sort + active-cell count.

__global__ void k_prefix(const int* __restrict__ hist,
                         int* __restrict__ off, int* __restrict__ nactp) {
    if (threadIdx.x == 0 && blockIdx.x == 0) {
        int acc = 0;
        for (int k = 10; k >= 1; --k) { off[k] = acc; acc += hist[k]; }
        *nactp = acc;
    }
}

// k_order: scatter cells into k-descending order (within-bin order arbitrary).

__global__ __launch_bounds__(256) void k_order(const int* __restrict__ kcnt,
                                               const int* __restrict__ off,
                                               int* __restrict__ rank,
                                               int* __restrict__ order) {
    int m = blockIdx.x * 256 + threadIdx.x;
    if (m >= M_CELLS) return;
    int k = kcnt[m];
    if (k > 0) {
        int pos = off[k] + atomicAdd(rank + k, 1);
        order[pos] = m;
    }
}

// k_gx_all: ALL frames' winner-pixel feature gather, pixel-order (coalesced).
// Agx indexed [t][cell] directly.

__global__ __launch_bounds__(256) void k_gx_all(const float* __restrict__ feat_all,
                                                const int* __restrict__ ps,
                                                short* __restrict__ Agx) {
    int t = blockIdx.y;
    int p = blockIdx.x * 256 + threadIdx.x;
    int i = ps[(size_t)t * P_PIX + p];
    if (i < 0) return;
    const float* feat = feat_all + (size_t)t * C_FEAT * P_PIX;
    short* dst = Agx + ((size_t)t * NPAD + i) * 64;
    #pragma unroll
    for (int c8 = 0; c8 < 8; ++c8) {
        unsigned int pk[4];
        #pragma unroll
        for (int q = 0; q < 4; ++q) {
            float f0 = feat[(size_t)(c8 * 8 + 2 * q)     * P_PIX + p];
            float f1 = feat[(size_t)(c8 * 8 + 2 * q + 1) * P_PIX + p];
            pk[q] = (unsigned int)f2bf(f0) | ((unsigned int)f2bf(f1) << 16);
        }
        *(uint4*)(dst + c8 * 8) = make_uint4(pk[0], pk[1], pk[2], pk[3]);
    }
}

// ===================== weight pre-transforms (one dispatch) =====================

__device__ __forceinline__ void wprep_gru_item(int idx,
        const float* __restrict__ w_ih, const float* __restrict__ w_hh,
        short* __restrict__ wq) {
    int gp = idx & 1023, k8 = idx >> 10;
    int tau = gp >> 8, gl = gp & 255;
    unsigned int pk[4];
    #pragma unroll
    for (int q = 0; q < 4; ++q) {
        unsigned int h2[2];
        #pragma unroll
        for (int e = 0; e < 2; ++e) {
            int k = k8 * 8 + q * 2 + e;
            float v = 0.f;
            if (tau == 0)      v = (k < 64) ? w_ih[(size_t)gl * 64 + k]
                                            : w_hh[(size_t)gl * 256 + (k - 64)];
            else if (tau == 1) v = (k < 64) ? w_ih[(size_t)(256 + gl) * 64 + k]
                                            : w_hh[(size_t)(256 + gl) * 256 + (k - 64)];
            else if (tau == 2) v = (k < 64) ? w_ih[(size_t)(512 + gl) * 64 + k] : 0.f;
            else               v = (k < 64) ? 0.f
                                            : w_hh[(size_t)(512 + gl) * 256 + (k - 64)];
            h2[e] = f2bf(v);
        }
        pk[q] = h2[0] | (h2[1] << 16);
    }
    *(uint4*)(wq + (size_t)idx * 8) = make_uint4(pk[0], pk[1], pk[2], pk[3]);
}

__device__ __forceinline__ void wprep_conv_item(int idx, const float* __restrict__ w,
        short* __restrict__ wm, int OC, int CIN, int OCP, int CINP, int KS) {
    int oc  = idx % OCP;
    int t2  = idx / OCP;
    int ci8 = t2 % (CINP / 8);
    int tap = t2 / (CINP / 8);
    unsigned int pk[4];
    #pragma unroll
    for (int q = 0; q < 4; ++q) {
        unsigned int h[2];
        #pragma unroll
        for (int e = 0; e < 2; ++e) {
            int ci = ci8 * 8 + 2*q + e;
            float v = (oc < OC && ci < CIN)
                ? w[((size_t)oc * CIN + ci) * KS * KS + tap] : 0.f;
            h[e] = f2bf(v);
        }
        pk[q] = h[0] | (h[1] << 16);
    }
    *(uint4*)(wm + (size_t)idx * 8) = make_uint4(pk[0], pk[1], pk[2], pk[3]);
}

__global__ __launch_bounds__(256) void k_wprep_all(
        const float* __restrict__ w_ih, const float* __restrict__ w_hh,
        short* __restrict__ wq,
        const float* __restrict__ c1_w, short* __restrict__ wm1,
        const float* __restrict__ c2_w, short* __restrict__ wm2,
        const float* __restrict__ c3_w, short* __restrict__ wm3,
        const float* __restrict__ c4_w, short* __restrict__ wm4) {
    int idx = blockIdx.x * 256 + threadIdx.x;
    switch (blockIdx.y) {
    case 0: if (idx < 40 * 1024)    wprep_gru_item(idx, w_ih, w_hh, wq); break;
    case 1: if (idx < 49*32*128)    wprep_conv_item(idx, c1_w, wm1, 128, 256, 128, 256, 7); break;
    case 2: if (idx < 9*16*64)      wprep_conv_item(idx, c2_w, wm2,  64, 128,  64, 128, 3); break;
    case 3: if (idx < 9*8*64)       wprep_conv_item(idx, c3_w, wm3,  48,  64,  64,  64, 3); break;
    default: if (idx < 9*8*64)      wprep_conv_item(idx, c4_w, wm4,  48,  48,  64,  64, 3); break;
    }
}

// ===================== GRU: per-cell chains, ONE launch, no global sync ==========
// Cells sorted desc by update-count k; block owns 64 similar-k cells and runs
// their chains locally: j = 0..kmax-1 { stage x (Agx[cfr[cell][j]][cell]) + h
// (fp32 state -> bf16, swizzled LDS) -> v4 MFMA body (A-reuse 4x, zero-tau skip)
// -> fused epilogue -> fp32 state }. Per-cell recurrence is independent, so no
// inter-block ordering is needed; within-block __syncthreads orders the steps.

__global__ __launch_bounds__(256) void k_gruseq(
        const short* __restrict__ Agx,
        const short* __restrict__ wq,
        const float* __restrict__ b_ih, const float* __restrict__ b_hh,
        const int* __restrict__ order, const int* __restrict__ kcnt,
        const signed char* __restrict__ cfr,
        const int* __restrict__ nactp,
        float* __restrict__ state) {
    const int nact = *nactp;
    const int base = blockIdx.x * 64;
    if (base >= nact) return;

    __shared__ alignas(16) char B[64 * 640];    // [cell][320 bf16], swizzled
    __shared__ int ml[64], kcs[64], tf[64];
    __shared__ int kmax_s;
    const int tid = threadIdx.x;
    const int w = tid >> 6, l = tid & 63, u = l & 15, s = l >> 4;

    if (tid < 64) {
        int i = base + tid; if (i > nact - 1) i = nact - 1;   // tail clamp
        int m = order[i];
        ml[tid] = m;
        kcs[tid] = (base + tid < nact) ? kcnt[m] : 0;         // dead for clamped
        if (tid == 0) kmax_s = kcnt[order[base]];             // desc order -> block max
    }
    __syncthreads();
    const int kmax = kmax_s;

    for (int j = 0; j < kmax; ++j) {
        if (tid < 64)
            tf[tid] = (j < kcs[tid]) ? (int)cfr[ml[tid] * 10 + j] : -1;
        __syncthreads();

        // stage x-part (k 0..63): Agx row of this step's frame (zeros if dead)
        for (int e = tid; e < 512; e += 256) {
            int cell = e >> 3, kc = e & 7;
            int t = tf[cell];
            uint4 v = make_uint4(0, 0, 0, 0);
            if (t >= 0)
                v = *(const uint4*)(Agx + ((size_t)t * NPAD + ml[cell]) * 64 + kc * 8);
            int dst = (cell * 640 + kc * 16) ^ ((cell & 7) << 4);
            *(uint4*)(B + dst) = v;
        }
        // stage h-part (k 64..319) from fp32 state (init 0 via memset -> j=0 free)
        for (int e = tid; e < 2048; e += 256) {
            int cell = e >> 5, kc = e & 31;
            const float* sp = state + (size_t)ml[cell] * D_MEM + kc * 8;
            float4 v0 = *(const float4*)sp;
            float4 v1 = *(const float4*)(sp + 4);
            int dst = (cell * 640 + 128 + kc * 16) ^ ((cell & 7) << 4);
            *(uint4*)(B + dst) = pack8u(v0, v1);
        }
        __syncthreads();

        #pragma unroll 1
        for (int g16 = w; g16 < 16; g16 += 4) {
            f32x4 aR[4], aZ[4], aI[4], aH[4];
            #pragma unroll
            for (int cf = 0; cf < 4; ++cf) {
                aR[cf] = (f32x4){0.f,0.f,0.f,0.f}; aZ[cf] = (f32x4){0.f,0.f,0.f,0.f};
                aI[cf] = (f32x4){0.f,0.f,0.f,0.f}; aH[cf] = (f32x4){0.f,0.f,0.f,0.f};
            }

            // ck 0-1: x-part (r, z, inn)
            #pragma unroll
            for (int ck = 0; ck < 2; ++ck) {
                s16x8 b[4];
                #pragma unroll
                for (int cf = 0; cf < 4; ++cf) {
                    int cell = 16 * cf + u;
                    int byte = (cell * 640 + ck * 64 + s * 16) ^ ((cell & 7) << 4);
                    b[cf] = *(const s16x8*)(B + byte);
                }
                const short* wr = wq + ((size_t)(ck * 4 + s) * 1024 + g16 * 16 + u) * 8;
                s16x8 ar = *(const s16x8*)(wr);
                s16x8 az = *(const s16x8*)(wr + 256 * 8);
                s16x8 an = *(const s16x8*)(wr + 512 * 8);
                #pragma unroll
                for (int cf = 0; cf < 4; ++cf) {
                    aR[cf] = __builtin_amdgcn_mfma_f32_16x16x32_bf16(ar, b[cf], aR[cf], 0, 0, 0);
                    aZ[cf] = __builtin_amdgcn_mfma_f32_16x16x32_bf16(az, b[cf], aZ[cf], 0, 0, 0);
                    aI[cf] = __builtin_amdgcn_mfma_f32_16x16x32_bf16(an, b[cf], aI[cf], 0, 0, 0);
                }
            }
            // ck 2-9: h-part (r, z, hn)
            #pragma unroll 2
            for (int ck = 2; ck < 10; ++ck) {
                s16x8 b[4];
                #pragma unroll
                for (int cf = 0; cf < 4; ++cf) {
                    int cell = 16 * cf + u;
                    int byte = (cell * 640 + ck * 64 + s * 16) ^ ((cell & 7) << 4);
                    b[cf] = *(const s16x8*)(B + byte);
                }
                const short* wr = wq + ((size_t)(ck * 4 + s) * 1024 + g16 * 16 + u) * 8;
                s16x8 ar = *(const s16x8*)(wr);
                s16x8 az = *(const s16x8*)(wr + 256 * 8);
                s16x8 an = *(const s16x8*)(wr + 768 * 8);
                #pragma unroll
                for (int cf = 0; cf < 4; ++cf) {
                    aR[cf] = __builtin_amdgcn_mfma_f32_16x16x32_bf16(ar, b[cf], aR[cf], 0, 0, 0);
                    aZ[cf] = __builtin_amdgcn_mfma_f32_16x16x32_bf16(az, b[cf], aZ[cf], 0, 0, 0);
                    aH[cf] = __builtin_amdgcn_mfma_f32_16x16x32_bf16(an, b[cf], aH[cf], 0, 0, 0);
                }
            }

            // epilogue: d = g16*16 + 4s + r, cells 16cf+u; live iff tf >= 0
            const int d0 = g16 * 16 + 4 * s;
            #pragma unroll
            for (int cf = 0; cf < 4; ++cf) {
                if (tf[16 * cf + u] >= 0) {
                    float* sp = state + (size_t)ml[16 * cf + u] * D_MEM;
                    float4 h = *(const float4*)(sp + d0);
                    float hv[4] = {h.x, h.y, h.z, h.w};
                    float ov[4];
                    #pragma unroll
                    for (int r = 0; r < 4; ++r) {
                        int d = d0 + r;
                        float rr = aR[cf][r] + b_ih[d]       + b_hh[d];
                        float zz = aZ[cf][r] + b_ih[256 + d] + b_hh[256 + d];
                        float ii = aI[cf][r] + b_ih[512 + d];
                        float hh = aH[cf][r] + b_hh[512 + d];
                        float rv = 1.f / (1.f + expf(-rr));
                        float zv = 1.f / (1.f + expf(-zz));
                        float nv = tanhf(ii + rv * hh);
                        ov[r] = (1.f - zv) * nv + zv * hv[r];
                    }
                    *(float4*)(sp + d0) = make_float4(ov[0], ov[1], ov[2], ov[3]);
                }
            }
        }
        __syncthreads();   // order step j's state writes/B reuse before step j+1
    }
}

// ===================== MFMA implicit-GEMM conv, fully fused BN =====================

template<int CINP, int KS, int TLY, bool NORM, bool STATS, bool F32OUT, bool F32IN>
__global__ __launch_bounds__(256) void k_cmfma(const void* __restrict__ in,
                                               const short* __restrict__ wm,
                                               int OCT,
                                               void* __restrict__ out,
                                               int OCS,
                                               const float* __restrict__ sums_in,
                                               const float* __restrict__ sums2_in,
                                               const float* __restrict__ g_in,
                                               const float* __restrict__ b_in,
                                               int OCPREV,
                                               float* __restrict__ sums_out,
                                               float* __restrict__ sums2_out) {
    constexpr int PAD = KS / 2;
    constexpr int BH  = 4 * TLY;
    constexpr int PTW_X = 16 + KS - 1;
    constexpr int PTW_Y = BH + KS - 1;
    __shared__ alignas(16) char patch[PTW_Y * PTW_X * 64];
    __shared__ float scl[NORM ? CINP : 1], shf[NORM ? CINP : 1];
    __shared__ float st1[4][64], st2[4][64];

    const int tid = threadIdx.x;
    const int w   = tid >> 6;
    const int l   = tid & 63;
    const int u   = l & 15;
    const int s   = l >> 4;

    const int x0  = 3 + 16 * blockIdx.x;
    const int y0  = 3 + BH * blockIdx.y;
    const int oc0 = 64 * blockIdx.z;

    if constexpr (NORM) {
        for (int c = tid; c < CINP; c += 256) {
            float sc = 0.f, sh = 0.f;
            if (c < OCPREV) {
                float mu  = sums_in[c] * (1.f / M_CELLS);
                float var = sums2_in[c] * (1.f / M_CELLS) - mu * mu;
                float rs  = rsqrtf(var + 1e-5f);
                sc = g_in[c] * rs;
                sh = b_in[c] - mu * rs * g_in[c];
            }
            scl[c] = sc; shf[c] = sh;
        }
    }

    f32x4 acc[TLY][4];   // [yy][o]
    #pragma unroll
    for (int yy = 0; yy < TLY; ++yy)
        #pragma unroll
        for (int o = 0; o < 4; ++o)
            acc[yy][o] = (f32x4){0.f, 0.f, 0.f, 0.f};

    for (int ci0 = 0; ci0 < CINP; ci0 += 32) {
        __syncthreads();
        for (int e = tid; e < PTW_Y * PTW_X * 4; e += 256) {
            int c8 = e & 3;
            int pp = e >> 2;
            int px = pp % PTW_X, py = pp / PTW_X;
            int gy = y0 - PAD + py, gx = x0 - PAD + px;
            bool inb = (gy >= 3) && (gy < 253) && (gx >= 3) && (gx < 253);
            uint4 v = make_uint4(0, 0, 0, 0);
            if constexpr (F32IN) {
                if (inb) {
                    int m = (gy - 3) * MAP_W + (gx - 3);
                    const float* sp = (const float*)in + (size_t)m * 256 + ci0 + c8 * 8;
                    float4 v0 = *(const float4*)sp;
                    float4 v1 = *(const float4*)(sp + 4);
                    v = pack8u(v0, v1);
                }
            } else {
                v = *(const uint4*)((const short*)in + ((size_t)gy * PW + gx) * CINP
                                    + ci0 + c8 * 8);
                if constexpr (NORM) {
                    int cb = ci0 + c8 * 8;
                    unsigned int uu[4] = {v.x, v.y, v.z, v.w};
                    unsigned int ro[4];
                    #pragma unroll
                    for (int q = 0; q < 4; ++q) {
                        float f0 = bf2f((unsigned short)(uu[q] & 0xffffu));
                        float f1 = bf2f((unsigned short)(uu[q] >> 16));
                        f0 = fmaxf(fmaf(f0, scl[cb + 2*q],     shf[cb + 2*q]),     0.f);
                        f1 = fmaxf(fmaf(f1, scl[cb + 2*q + 1], shf[cb + 2*q + 1]), 0.f);
                        ro[q] = (unsigned int)f2bf(f0) | ((unsigned int)f2bf(f1) << 16);
                    }
                    v = make_uint4(ro[0], ro[1], ro[2], ro[3]);
                }
                if (!inb) v = make_uint4(0, 0, 0, 0);
            }
            int lb = (((py * PTW_X + px) * 64) + c8 * 16) ^ ((px & 3) << 4);
            *(uint4*)(patch + lb) = v;
        }
        __syncthreads();

        const short* wb = wm + ((size_t)(ci0 / 8 + s) * OCT + oc0 + u) * 8;

        for (int ky = 0; ky < KS; ++ky) {
            for (int kx = 0; kx < KS; ++kx) {
                const int tap = ky * KS + kx;
                const short* wt = wb + (size_t)tap * (CINP / 8) * OCT * 8;
                s16x8 a[4];
                #pragma unroll
                for (int o = 0; o < 4; ++o)
                    a[o] = *(const s16x8*)(wt + o * 16 * 8);
                const int px = kx + u;
                const int lb0 = ((px * 64) + s * 16) ^ ((px & 3) << 4);
                #pragma unroll
                for (int yy = 0; yy < TLY; ++yy) {
                    int py = TLY * w + yy + ky;
                    s16x8 b = *(const s16x8*)(patch + py * PTW_X * 64 + lb0);
                    #pragma unroll
                    for (int o = 0; o < 4; ++o)
                        acc[yy][o] = __builtin_amdgcn_mfma_f32_16x16x32_bf16(
                            a[o], b, acc[yy][o], 0, 0, 0);
                }
            }
        }
    }

    const int gx = x0 + u;
    const bool colok = (gx < 253);

    if constexpr (STATS) {
        float s1[16], s2[16];
        #pragma unroll
        for (int e = 0; e < 16; ++e) { s1[e] = 0.f; s2[e] = 0.f; }
        #pragma unroll
        for (int yy = 0; yy < TLY; ++yy) {
            int gy = y0 + TLY * w + yy;
            if (colok && gy < 253) {
                #pragma unroll
                for (int o = 0; o < 4; ++o)
                    #pragma unroll
                    for (int r = 0; r < 4; ++r) {
                        float v = acc[yy][o][r];
                        s1[o*4+r] += v; s2[o*4+r] += v * v;
                    }
            }
        }
        #pragma unroll
        for (int off = 1; off < 16; off <<= 1)
            #pragma unroll
            for (int e = 0; e < 16; ++e) {
                s1[e] += __shfl_xor(s1[e], off, 64);
                s2[e] += __shfl_xor(s2[e], off, 64);
            }
        if (u == 0) {
            #pragma unroll
            for (int e = 0; e < 16; ++e) {
                int ch = (e >> 2) * 16 + s * 4 + (e & 3);
                st1[w][ch] = s1[e]; st2[w][ch] = s2[e];
            }
        }
        __syncthreads();
        if (tid < 64) {
            float a1 = st1[0][tid] + st1[1][tid] + st1[2][tid] + st1[3][tid];
            float a2 = st2[0][tid] + st2[1][tid] + st2[2][tid] + st2[3][tid];
            atomicAdd(sums_out  + oc0 + tid, a1);
            atomicAdd(sums2_out + oc0 + tid, a2);
        }
    }

    if (!colok) return;
    #pragma unroll
    for (int yy = 0; yy < TLY; ++yy) {
        int gy = y0 + TLY * w + yy;
        if (gy >= 253) continue;
        #pragma unroll
        for (int o = 0; o < 4; ++o) {
            int oc = oc0 + o * 16 + s * 4;
            if constexpr (F32OUT) {
                int m = (gy - 3) * MAP_W + (gx - 3);
                float* op = (float*)out + (size_t)m * 48 + oc;
                #pragma unroll
                for (int r = 0; r < 4; ++r)
                    if (oc + r < 48) op[r] = acc[yy][o][r];
            } else {
                short* op = (short*)out + ((size_t)gy * PW + gx) * OCS + oc;
                unsigned int w0 = f2bf(acc[yy][o][0]) | ((unsigned int)f2bf(acc[yy][o][1]) << 16);
                unsigned int w1 = f2bf(acc[yy][o][2]) | ((unsigned int)f2bf(acc[yy][o][3]) << 16);
                *(uint2*)op = make_uint2(w0, w1);
            }
        }
    }
}

// ===================== conv5 (1x1) + bias, fused bn4(from sums)+relu =====================

__global__ __launch_bounds__(256) void k_conv5(const float* __restrict__ x4, // [M][48]
                                               const float* __restrict__ w,
                                               const float* __restrict__ bias,
                                               const float* __restrict__ sums4,
                                               const float* __restrict__ sums24,
                                               const float* __restrict__ g4,
                                               const float* __restrict__ b4,
                                               float* __restrict__ sem) {
    __shared__ float wl[N_CLS * 48];
    __shared__ float scl[48], shf[48], bl[N_CLS];
    int tid = threadIdx.x;
    for (int e = tid; e < N_CLS * 48; e += 256) wl[e] = w[e];
    if (tid < 48) {
        float mu  = sums4[tid] * (1.f / M_CELLS);
        float var = sums24[tid] * (1.f / M_CELLS) - mu * mu;
        float rs  = rsqrtf(var + 1e-5f);
        scl[tid] = g4[tid] * rs;
        shf[tid] = b4[tid] - mu * rs * g4[tid];
    }
    if (tid < N_CLS) bl[tid] = bias[tid];
    __syncthreads();
    int p = blockIdx.x * 256 + tid;
    if (p >= M_CELLS) return;
    float inr[48];
    const float4* xp = (const float4*)(x4 + (size_t)p * 48);
    #pragma unroll
    for (int q = 0; q < 12; ++q) {
        float4 v = xp[q];
        inr[4*q+0] = v.x; inr[4*q+1] = v.y; inr[4*q+2] = v.z; inr[4*q+3] = v.w;
    }
    #pragma unroll
    for (int c = 0; c < 48; ++c)
        inr[c] = fmaxf(fmaf(inr[c], scl[c], shf[c]), 0.f);
    #pragma unroll
    for (int o = 0; o < N_CLS; ++o) {
        float a = bl[o];
        #pragma unroll
        for (int c = 0; c < 48; ++c) a = fmaf(inr[c], wl[o * 48 + c], a);
        sem[(size_t)o * M_CELLS + p] = a;
    }
}

// ===================== host launcher =====================

extern "C" void kernel_launch(void* const* d_in, const int* in_sizes, int n_in,
                              void* d_out, int out_size, void* d_ws, size_t ws_size,
                              hipStream_t stream) {
    (void)in_sizes; (void)n_in; (void)out_size; (void)ws_size;

    const float* features = (const float*)d_in[0];
    const int*   proj     = (const int*)d_in[1];
    const int*   mask     = (const int*)d_in[2];
    const float* heights  = (const float*)d_in[3];
    const float* w_ih  = (const float*)d_in[6];
    const float* w_hh  = (const float*)d_in[7];
    const float* b_ih  = (const float*)d_in[8];
    const float* b_hh  = (const float*)d_in[9];
    const float* c1_w  = (const float*)d_in[10];
    const float* bn1_g = (const float*)d_in[11];
    const float* bn1_b = (const float*)d_in[12];
    const float* c2_w  = (const float*)d_in[13];
    const float* bn2_g = (const float*)d_in[14];
    const float* bn2_b = (const float*)d_in[15];
    const float* c3_w  = (const float*)d_in[16];
    const float* bn3_g = (const float*)d_in[17];
    const float* bn3_b = (const float*)d_in[18];
    const float* c4_w  = (const float*)d_in[19];
    const float* bn4_g = (const float*)d_in[20];
    const float* bn4_b = (const float*)d_in[21];
    const float* c5_w  = (const float*)d_in[22];
    const float* c5_b  = (const float*)d_in[23];

    // ---- workspace layout; [state|packed|hist/rank/off/nact|sums|sums2] zeroed ----
    char* ws = (char*)d_ws;
    float* state = (float*)(ws);                                   // 64.0 MB
    unsigned long long* packed = (unsigned long long*)(ws + 64000000); // 5.0 MB [T][M]
    int*   hist    = (int*)(ws + 69000064);                        // 16
    int*   rank    = (int*)(ws + 69000128);                        // 16
    int*   off     = (int*)(ws + 69000192);                        // 16
    int*   nactp   = (int*)(ws + 69000256);                        // 1
    float* sums    = (float*)(ws + 69001024);                      // 512 f
    float* sums2   = (float*)(ws + 69003072);                      // 512 f
    int*   ps      = (int*)(ws + 70000000);                        // 12.3 MB [T][P]
    int*   kcnt    = (int*)(ws + 83000000);                        // 250 KB
    signed char* cfr = (signed char*)(ws + 83300000);              // 625 KB [M][10]
    int*   order   = (int*)(ws + 84000000);                        // 250 KB
    short* Agx     = (short*)(ws + 86000000);                      // 80.0 MB [T][NPAD][64]
    short* wq      = (short*)(ws + 167000000);                     // 0.66 MB
    short* wm1     = (short*)(ws + 168000000);                     // 3.2 MB
    short* wm2     = (short*)(ws + 171300000);
    short* wm3     = (short*)(ws + 171500000);
    short* wm4     = (short*)(ws + 171600000);
    short* x1_cl   = (short*)(ws + 172000000);                     // 18.2 MB
    short* x2_cl   = (short*)(ws + 191000000);                     //  9.1 MB
    short* x3_cl   = (short*)(ws + 201000000);                     //  9.1 MB
    float* x4      = (float*)(ws + 211000000);                     // 12.0 MB

    // one zero-memset: state + packed + hist/rank/off/nact + sums + sums2
    hipMemsetAsync(ws, 0, 69005120, stream);

    // all weight pre-transforms in one dispatch
    k_wprep_all<<<dim3(784, 5), 256, 0, stream>>>(w_ih, w_hh, wq,
                                                  c1_w, wm1, c2_w, wm2,
                                                  c3_w, wm3, c4_w, wm4);

    const int PB = P_PIX / 256;                  // 1200
    const int MB = (M_CELLS + 255) / 256;        // 245
    const int CB = NPAD / 64;                    // 977

    // frame-parallel scan + chain scheduling
    k_scatter_all<<<dim3(PB, T_FRAMES), 256, 0, stream>>>(
        (const int2*)proj, mask, heights, packed, ps);
    k_sched<<<MB, 256, 0, stream>>>(packed, cfr, kcnt, ps, hist, (float*)d_out);
    k_prefix<<<1, 64, 0, stream>>>(hist, off, nactp);
    k_order<<<MB, 256, 0, stream>>>(kcnt, off, rank, order);
    k_gx_all<<<dim3(PB, T_FRAMES), 256, 0, stream>>>(features, ps, Agx);

    // GRU: all per-cell chains in ONE launch (no global sync needed)
    k_gruseq<<<CB, 256, 0, stream>>>(Agx, wq, b_ih, b_hh,
                                     order, kcnt, cfr, nactp, state);

    // conv1 7x7 256->128: TLY=4 (2 blocks/CU), fp32 state input, stats out
    k_cmfma<256, 7, 4, false, true, false, true><<<dim3(16, 16, 2), 256, 0, stream>>>(
        state, wm1, 128, x1_cl, 128,
        nullptr, nullptr, nullptr, nullptr, 0, sums + 0, sums2 + 0);

    // conv2 3x3 128->64 (bn1 from sums fused in; stats out)
    k_cmfma<128, 3, 4, true, true, false, false><<<dim3(16, 16, 1), 256, 0, stream>>>(
        x1_cl, wm2, 64, x2_cl, 64,
        sums + 0, sums2 + 0, bn1_g, bn1_b, 128, sums + 128, sums2 + 128);

    // conv3 3x3 64->48 (bn2 in; stats out)
    k_cmfma<64, 3, 4, true, true, false, false><<<dim3(16, 16, 1), 256, 0, stream>>>(
        x2_cl, wm3, 64, x3_cl, 64,
        sums + 128, sums2 + 128, bn2_g, bn2_b, 64, sums + 192, sums2 + 192);

    // conv4 3x3 48->48 (bn3 in; stats out) -> compact f32 [M][48]
    k_cmfma<64, 3, 4, true, true, true, false><<<dim3(16, 16, 1), 256, 0, stream>>>(
        x3_cl, wm4, 64, x4, 48,
        sums + 192, sums2 + 192, bn3_g, bn3_b, 48, sums + 256, sums2 + 256);

    // conv5 1x1 48->20 + bias (bn4 from sums fused) -> sem
    k_conv5<<<MB, 256, 0, stream>>>(x4, c5_w, c5_b,
                                    sums + 256, sums2 + 256, bn4_g, bn4_b,
                                    (float*)d_out);
}

// Round 14
// 1218.793 us; speedup vs baseline: 2.1214x; 1.3682x over previous
//
#include <hip/hip_runtime.h>
#include <math.h>

// ---------------- problem dims (fixed by setup_inputs) ----------------
#define T_FRAMES 10
#define C_FEAT   64
#define IMG_H    480
#define IMG_W    640
#define P_PIX    (IMG_H*IMG_W)     // 307200
#define MAP_H    250
#define MAP_W    250
#define M_CELLS  (MAP_H*MAP_W)     // 62500
#define D_MEM    256
#define N_CLS    20
#define NPAD     62528             // M_CELLS padded to 64

// padded channels-last plane geometry for bf16 activations: interior origin (3,3)
#define PW  272
#define PH  262
#define PP  (PH*PW)                // 71264 px per padded plane

typedef __attribute__((ext_vector_type(8))) short s16x8;   // 8 bf16 (4 VGPR)
typedef __attribute__((ext_vector_type(4))) float f32x4;   // MFMA acc

__device__ __forceinline__ unsigned short f2bf(float f) {
    unsigned int u = __float_as_uint(f);
    u += 0x7fffu + ((u >> 16) & 1u);      // RNE
    return (unsigned short)(u >> 16);
}
__device__ __forceinline__ float bf2f(unsigned short b) {
    return __uint_as_float(((unsigned int)b) << 16);
}
__device__ __forceinline__ uint4 pack8u(float4 a, float4 b) {
    uint4 r;
    r.x = (unsigned int)f2bf(a.x) | ((unsigned int)f2bf(a.y) << 16);
    r.y = (unsigned int)f2bf(a.z) | ((unsigned int)f2bf(a.w) << 16);
    r.z = (unsigned int)f2bf(b.x) | ((unsigned int)f2bf(b.y) << 16);
    r.w = (unsigned int)f2bf(b.z) | ((unsigned int)f2bf(b.w) << 16);
    return r;
}

// ===================== scan phase (frame-parallel) =====================
// packed[t][m] = max over frame-t inlier pixels of (height_bits<<32 | pixel).
// u64 atomicMax = lexicographic (max height, then max pixel) == reference tie rule.

__global__ __launch_bounds__(256) void k_scatter_all(const int2* __restrict__ proj,
                                                     const int* __restrict__ mask,
                                                     const float* __restrict__ heights,
                                                     unsigned long long* __restrict__ packed,
                                                     int* __restrict__ ps) {
    int t = blockIdx.y;
    int p = blockIdx.x * 256 + threadIdx.x;           // grid.x*256 == P_PIX exactly
    size_t gp = (size_t)t * P_PIX + p;
    ps[gp] = -1;                                      // init inverse map in-kernel
    if (mask[gp]) return;                             // outlier: never wins
    int2 pr = proj[gp];
    int idx = MAP_W * pr.y + pr.x;
    float mh = heights[gp] + 1000.0f;                 // > 0 -> uint order == float order
    unsigned long long pk = ((unsigned long long)__float_as_uint(mh) << 32)
                            | (unsigned int)p;
    atomicMax(packed + (size_t)t * M_CELLS + idx, pk);
}

// k_sched: per cell, walk the 10 frame-maxima in registers; emit per-frame
// updlists/slots/winner-pixel map, plus final hmap/observed direct to d_out.

__global__ __launch_bounds__(256) void k_sched(const unsigned long long* __restrict__ packed,
                                               int* __restrict__ updlist,   // [T][NPAD]
                                               int* __restrict__ ps,        // [T][P_PIX]
                                               int* __restrict__ count,     // [T]
                                               float* __restrict__ out) {
    int m = blockIdx.x * 256 + threadIdx.x;
    if (m >= M_CELLS) return;
    unsigned int pv = 0;                               // == 0.0f (hmap init)
    bool any = false;
    #pragma unroll
    for (int t = 0; t < T_FRAMES; ++t) {
        unsigned long long pk = packed[(size_t)t * M_CELLS + m];
        unsigned int hb = (unsigned int)(pk >> 32);
        if (hb > pv) {                                 // strict: matches new_hmap > hmap
            int slot = atomicAdd(count + t, 1);
            updlist[t * NPAD + slot] = m;
            ps[(size_t)t * P_PIX + (pk & 0xffffffffu)] = slot;
            pv = hb;
            any = true;
        }
    }
    out[(size_t)N_CLS * M_CELLS + m] = any ? 1.0f : 0.0f;
    out[(size_t)N_CLS * M_CELLS + M_CELLS + m] = __uint_as_float(pv);
}

// k_gx_all: ALL frames' winner-pixel feature gather, pixel-order (coalesced).

__global__ __launch_bounds__(256) void k_gx_all(const float* __restrict__ feat_all,
                                                const int* __restrict__ ps,
                                                short* __restrict__ Agx) {
    int t = blockIdx.y;
    int p = blockIdx.x * 256 + threadIdx.x;
    int i = ps[(size_t)t * P_PIX + p];
    if (i < 0) return;
    const float* feat = feat_all + (size_t)t * C_FEAT * P_PIX;
    short* dst = Agx + ((size_t)t * NPAD + i) * 64;
    #pragma unroll
    for (int c8 = 0; c8 < 8; ++c8) {
        unsigned int pk[4];
        #pragma unroll
        for (int q = 0; q < 4; ++q) {
            float f0 = feat[(size_t)(c8 * 8 + 2 * q)     * P_PIX + p];
            float f1 = feat[(size_t)(c8 * 8 + 2 * q + 1) * P_PIX + p];
            pk[q] = (unsigned int)f2bf(f0) | ((unsigned int)f2bf(f1) << 16);
        }
        *(uint4*)(dst + c8 * 8) = make_uint4(pk[0], pk[1], pk[2], pk[3]);
    }
}

// ===================== weight pre-transforms (one dispatch) =====================

__device__ __forceinline__ void wprep_gru_item(int idx,
        const float* __restrict__ w_ih, const float* __restrict__ w_hh,
        short* __restrict__ wq) {
    int gp = idx & 1023, k8 = idx >> 10;
    int tau = gp >> 8, gl = gp & 255;
    unsigned int pk[4];
    #pragma unroll
    for (int q = 0; q < 4; ++q) {
        unsigned int h2[2];
        #pragma unroll
        for (int e = 0; e < 2; ++e) {
            int k = k8 * 8 + q * 2 + e;
            float v = 0.f;
            if (tau == 0)      v = (k < 64) ? w_ih[(size_t)gl * 64 + k]
                                            : w_hh[(size_t)gl * 256 + (k - 64)];
            else if (tau == 1) v = (k < 64) ? w_ih[(size_t)(256 + gl) * 64 + k]
                                            : w_hh[(size_t)(256 + gl) * 256 + (k - 64)];
            else if (tau == 2) v = (k < 64) ? w_ih[(size_t)(512 + gl) * 64 + k] : 0.f;
            else               v = (k < 64) ? 0.f
                                            : w_hh[(size_t)(512 + gl) * 256 + (k - 64)];
            h2[e] = f2bf(v);
        }
        pk[q] = h2[0] | (h2[1] << 16);
    }
    *(uint4*)(wq + (size_t)idx * 8) = make_uint4(pk[0], pk[1], pk[2], pk[3]);
}

__device__ __forceinline__ void wprep_conv_item(int idx, const float* __restrict__ w,
        short* __restrict__ wm, int OC, int CIN, int OCP, int CINP, int KS) {
    int oc  = idx % OCP;
    int t2  = idx / OCP;
    int ci8 = t2 % (CINP / 8);
    int tap = t2 / (CINP / 8);
    unsigned int pk[4];
    #pragma unroll
    for (int q = 0; q < 4; ++q) {
        unsigned int h[2];
        #pragma unroll
        for (int e = 0; e < 2; ++e) {
            int ci = ci8 * 8 + 2*q + e;
            float v = (oc < OC && ci < CIN)
                ? w[((size_t)oc * CIN + ci) * KS * KS + tap] : 0.f;
            h[e] = f2bf(v);
        }
        pk[q] = h[0] | (h[1] << 16);
    }
    *(uint4*)(wm + (size_t)idx * 8) = make_uint4(pk[0], pk[1], pk[2], pk[3]);
}

__global__ __launch_bounds__(256) void k_wprep_all(
        const float* __restrict__ w_ih, const float* __restrict__ w_hh,
        short* __restrict__ wq,
        const float* __restrict__ c1_w, short* __restrict__ wm1,
        const float* __restrict__ c2_w, short* __restrict__ wm2,
        const float* __restrict__ c3_w, short* __restrict__ wm3,
        const float* __restrict__ c4_w, short* __restrict__ wm4) {
    int idx = blockIdx.x * 256 + threadIdx.x;
    switch (blockIdx.y) {
    case 0: if (idx < 40 * 1024)    wprep_gru_item(idx, w_ih, w_hh, wq); break;
    case 1: if (idx < 49*32*128)    wprep_conv_item(idx, c1_w, wm1, 128, 256, 128, 256, 7); break;
    case 2: if (idx < 9*16*64)      wprep_conv_item(idx, c2_w, wm2,  64, 128,  64, 128, 3); break;
    case 3: if (idx < 9*8*64)       wprep_conv_item(idx, c3_w, wm3,  48,  64,  64,  64, 3); break;
    default: if (idx < 9*8*64)      wprep_conv_item(idx, c4_w, wm4,  48,  48,  64,  64, 3); break;
    }
}

// ===================== GRU GEMM v4 (A-reuse 4x, zero-tau skip) =====================
// Block = 64 cells, 256 thr = 4 waves. B (64 cells x 320 k bf16) staged ONCE in
// XOR-swizzled LDS (40KB). Wave w handles gate groups g16 in {w, w+4, w+8, w+12};
// per (g16, ck): 3 A-loads (r, z, inn-or-hn; the other tau's rows are exact zeros
// -> skipping is bit-identical), 4 B ds_reads, 12 MFMA -> A-reuse 4.

__global__ __launch_bounds__(256) void k_grumm4(
        const short* __restrict__ Agx_t,
        const short* __restrict__ wq,
        const float* __restrict__ b_ih, const float* __restrict__ b_hh,
        const int* __restrict__ updlist_t, const int* __restrict__ count_t,
        float* __restrict__ state) {
    int n = *count_t;
    int base = blockIdx.x * 64;
    if (base >= n) return;

    __shared__ alignas(16) char B[64 * 640];    // [cell][320 bf16], swizzled
    __shared__ int ml[64];
    const int tid = threadIdx.x;
    if (tid < 64) {
        int i = base + tid; if (i > n - 1) i = n - 1;   // tail clamp (no write later)
        ml[tid] = updlist_t[i];
    }
    __syncthreads();

    // stage x-part (k 0..63) from Agx: 512 x 16B
    for (int e = tid; e < 512; e += 256) {
        int cell = e >> 3, kc = e & 7;
        uint4 v = *(const uint4*)(Agx_t + ((size_t)(base + cell)) * 64 + kc * 8);
        int dst = (cell * 640 + kc * 16) ^ ((cell & 7) << 4);
        *(uint4*)(B + dst) = v;
    }
    // stage h-part (k 64..319) from fp32 state, convert: 2048 x 16B
    for (int e = tid; e < 2048; e += 256) {
        int cell = e >> 5, kc = e & 31;
        const float* sp = state + (size_t)ml[cell] * D_MEM + kc * 8;
        float4 v0 = *(const float4*)sp;
        float4 v1 = *(const float4*)(sp + 4);
        int dst = (cell * 640 + 128 + kc * 16) ^ ((cell & 7) << 4);
        *(uint4*)(B + dst) = pack8u(v0, v1);
    }
    __syncthreads();

    const int w = tid >> 6, l = tid & 63, u = l & 15, s = l >> 4;

    #pragma unroll 1
    for (int g16 = w; g16 < 16; g16 += 4) {
        f32x4 aR[4], aZ[4], aI[4], aH[4];
        #pragma unroll
        for (int cf = 0; cf < 4; ++cf) {
            aR[cf] = (f32x4){0.f,0.f,0.f,0.f}; aZ[cf] = (f32x4){0.f,0.f,0.f,0.f};
            aI[cf] = (f32x4){0.f,0.f,0.f,0.f}; aH[cf] = (f32x4){0.f,0.f,0.f,0.f};
        }

        #pragma unroll
        for (int ck = 0; ck < 10; ++ck) {
            s16x8 b[4];
            #pragma unroll
            for (int cf = 0; cf < 4; ++cf) {
                int cell = 16 * cf + u;
                int byte = (cell * 640 + ck * 64 + s * 16) ^ ((cell & 7) << 4);
                b[cf] = *(const s16x8*)(B + byte);
            }
            const short* wr = wq + ((size_t)(ck * 4 + s) * 1024 + g16 * 16 + u) * 8;
            s16x8 ar = *(const s16x8*)(wr);                        // tau 0: r
            s16x8 az = *(const s16x8*)(wr + 256 * 8);              // tau 1: z
            s16x8 an = *(const s16x8*)(wr + (ck < 2 ? 512 : 768) * 8); // inn | hn
            #pragma unroll
            for (int cf = 0; cf < 4; ++cf) {
                aR[cf] = __builtin_amdgcn_mfma_f32_16x16x32_bf16(ar, b[cf], aR[cf], 0, 0, 0);
                aZ[cf] = __builtin_amdgcn_mfma_f32_16x16x32_bf16(az, b[cf], aZ[cf], 0, 0, 0);
                if (ck < 2)
                    aI[cf] = __builtin_amdgcn_mfma_f32_16x16x32_bf16(an, b[cf], aI[cf], 0, 0, 0);
                else
                    aH[cf] = __builtin_amdgcn_mfma_f32_16x16x32_bf16(an, b[cf], aH[cf], 0, 0, 0);
            }
        }

        // epilogue: d = g16*16 + 4s + r, cells 16cf+u
        const int d0 = g16 * 16 + 4 * s;
        float bi0[4], bh0[4], bi1[4], bh1[4], bi2[4], bh2[4];
        #pragma unroll
        for (int r = 0; r < 4; ++r) {
            int d = d0 + r;
            bi0[r] = b_ih[d];        bh0[r] = b_hh[d];
            bi1[r] = b_ih[256 + d];  bh1[r] = b_hh[256 + d];
            bi2[r] = b_ih[512 + d];  bh2[r] = b_hh[512 + d];
        }
        #pragma unroll
        for (int cf = 0; cf < 4; ++cf) {
            if (base + 16 * cf + u < n) {
                float* sp = state + (size_t)ml[16 * cf + u] * D_MEM;
                float4 h = *(const float4*)(sp + d0);
                float hv[4] = {h.x, h.y, h.z, h.w};
                float ov[4];
                #pragma unroll
                for (int r = 0; r < 4; ++r) {
                    float rr = aR[cf][r] + bi0[r] + bh0[r];
                    float zz = aZ[cf][r] + bi1[r] + bh1[r];
                    float ii = aI[cf][r] + bi2[r];
                    float hh = aH[cf][r] + bh2[r];
                    float rv = 1.f / (1.f + expf(-rr));
                    float zv = 1.f / (1.f + expf(-zz));
                    float nv = tanhf(ii + rv * hh);
                    ov[r] = (1.f - zv) * nv + zv * hv[r];
                }
                *(float4*)(sp + d0) = make_float4(ov[0], ov[1], ov[2], ov[3]);
            }
        }
    }
}

// ===================== MFMA implicit-GEMM conv, fully fused BN =====================
// TLY = output rows per wave (block = 16 x 4*TLY px). F32IN: read fp32 state
// directly (convert in staging). NORM: apply prev-layer relu(bn(x)) during
// staging; interior mask keeps pads 0. STATS: BN sums from f32 accumulators.

template<int CINP, int KS, int TLY, bool NORM, bool STATS, bool F32OUT, bool F32IN>
__global__ __launch_bounds__(256) void k_cmfma(const void* __restrict__ in,
                                               const short* __restrict__ wm,
                                               int OCT,
                                               void* __restrict__ out,
                                               int OCS,
                                               const float* __restrict__ sums_in,
                                               const float* __restrict__ sums2_in,
                                               const float* __restrict__ g_in,
                                               const float* __restrict__ b_in,
                                               int OCPREV,
                                               float* __restrict__ sums_out,
                                               float* __restrict__ sums2_out) {
    constexpr int PAD = KS / 2;
    constexpr int BH  = 4 * TLY;
    constexpr int PTW_X = 16 + KS - 1;
    constexpr int PTW_Y = BH + KS - 1;
    __shared__ alignas(16) char patch[PTW_Y * PTW_X * 64];
    __shared__ float scl[NORM ? CINP : 1], shf[NORM ? CINP : 1];
    __shared__ float st1[4][64], st2[4][64];

    const int tid = threadIdx.x;
    const int w   = tid >> 6;
    const int l   = tid & 63;
    const int u   = l & 15;
    const int s   = l >> 4;

    const int x0  = 3 + 16 * blockIdx.x;
    const int y0  = 3 + BH * blockIdx.y;
    const int oc0 = 64 * blockIdx.z;

    if constexpr (NORM) {
        for (int c = tid; c < CINP; c += 256) {
            float sc = 0.f, sh = 0.f;
            if (c < OCPREV) {
                float mu  = sums_in[c] * (1.f / M_CELLS);
                float var = sums2_in[c] * (1.f / M_CELLS) - mu * mu;
                float rs  = rsqrtf(var + 1e-5f);
                sc = g_in[c] * rs;
                sh = b_in[c] - mu * rs * g_in[c];
            }
            scl[c] = sc; shf[c] = sh;
        }
    }

    f32x4 acc[TLY][4];   // [yy][o]
    #pragma unroll
    for (int yy = 0; yy < TLY; ++yy)
        #pragma unroll
        for (int o = 0; o < 4; ++o)
            acc[yy][o] = (f32x4){0.f, 0.f, 0.f, 0.f};

    for (int ci0 = 0; ci0 < CINP; ci0 += 32) {
        __syncthreads();
        for (int e = tid; e < PTW_Y * PTW_X * 4; e += 256) {
            int c8 = e & 3;
            int pp = e >> 2;
            int px = pp % PTW_X, py = pp / PTW_X;
            int gy = y0 - PAD + py, gx = x0 - PAD + px;
            bool inb = (gy >= 3) && (gy < 253) && (gx >= 3) && (gx < 253);
            uint4 v = make_uint4(0, 0, 0, 0);
            if constexpr (F32IN) {
                if (inb) {
                    int m = (gy - 3) * MAP_W + (gx - 3);
                    const float* sp = (const float*)in + (size_t)m * 256 + ci0 + c8 * 8;
                    float4 v0 = *(const float4*)sp;
                    float4 v1 = *(const float4*)(sp + 4);
                    v = pack8u(v0, v1);
                }
            } else {
                v = *(const uint4*)((const short*)in + ((size_t)gy * PW + gx) * CINP
                                    + ci0 + c8 * 8);
                if constexpr (NORM) {
                    int cb = ci0 + c8 * 8;
                    unsigned int uu[4] = {v.x, v.y, v.z, v.w};
                    unsigned int ro[4];
                    #pragma unroll
                    for (int q = 0; q < 4; ++q) {
                        float f0 = bf2f((unsigned short)(uu[q] & 0xffffu));
                        float f1 = bf2f((unsigned short)(uu[q] >> 16));
                        f0 = fmaxf(fmaf(f0, scl[cb + 2*q],     shf[cb + 2*q]),     0.f);
                        f1 = fmaxf(fmaf(f1, scl[cb + 2*q + 1], shf[cb + 2*q + 1]), 0.f);
                        ro[q] = (unsigned int)f2bf(f0) | ((unsigned int)f2bf(f1) << 16);
                    }
                    v = make_uint4(ro[0], ro[1], ro[2], ro[3]);
                }
                if (!inb) v = make_uint4(0, 0, 0, 0);
            }
            int lb = (((py * PTW_X + px) * 64) + c8 * 16) ^ ((px & 3) << 4);
            *(uint4*)(patch + lb) = v;
        }
        __syncthreads();

        const short* wb = wm + ((size_t)(ci0 / 8 + s) * OCT + oc0 + u) * 8;

        for (int ky = 0; ky < KS; ++ky) {
            for (int kx = 0; kx < KS; ++kx) {
                const int tap = ky * KS + kx;
                const short* wt = wb + (size_t)tap * (CINP / 8) * OCT * 8;
                s16x8 a[4];
                #pragma unroll
                for (int o = 0; o < 4; ++o)
                    a[o] = *(const s16x8*)(wt + o * 16 * 8);
                const int px = kx + u;
                const int lb0 = ((px * 64) + s * 16) ^ ((px & 3) << 4);
                #pragma unroll
                for (int yy = 0; yy < TLY; ++yy) {
                    int py = TLY * w + yy + ky;
                    s16x8 b = *(const s16x8*)(patch + py * PTW_X * 64 + lb0);
                    #pragma unroll
                    for (int o = 0; o < 4; ++o)
                        acc[yy][o] = __builtin_amdgcn_mfma_f32_16x16x32_bf16(
                            a[o], b, acc[yy][o], 0, 0, 0);
                }
            }
        }
    }

    const int gx = x0 + u;
    const bool colok = (gx < 253);

    if constexpr (STATS) {
        float s1[16], s2[16];
        #pragma unroll
        for (int e = 0; e < 16; ++e) { s1[e] = 0.f; s2[e] = 0.f; }
        #pragma unroll
        for (int yy = 0; yy < TLY; ++yy) {
            int gy = y0 + TLY * w + yy;
            if (colok && gy < 253) {
                #pragma unroll
                for (int o = 0; o < 4; ++o)
                    #pragma unroll
                    for (int r = 0; r < 4; ++r) {
                        float v = acc[yy][o][r];
                        s1[o*4+r] += v; s2[o*4+r] += v * v;
                    }
            }
        }
        #pragma unroll
        for (int off = 1; off < 16; off <<= 1)
            #pragma unroll
            for (int e = 0; e < 16; ++e) {
                s1[e] += __shfl_xor(s1[e], off, 64);
                s2[e] += __shfl_xor(s2[e], off, 64);
            }
        if (u == 0) {
            #pragma unroll
            for (int e = 0; e < 16; ++e) {
                int ch = (e >> 2) * 16 + s * 4 + (e & 3);
                st1[w][ch] = s1[e]; st2[w][ch] = s2[e];
            }
        }
        __syncthreads();
        if (tid < 64) {
            float a1 = st1[0][tid] + st1[1][tid] + st1[2][tid] + st1[3][tid];
            float a2 = st2[0][tid] + st2[1][tid] + st2[2][tid] + st2[3][tid];
            atomicAdd(sums_out  + oc0 + tid, a1);
            atomicAdd(sums2_out + oc0 + tid, a2);
        }
    }

    if (!colok) return;
    #pragma unroll
    for (int yy = 0; yy < TLY; ++yy) {
        int gy = y0 + TLY * w + yy;
        if (gy >= 253) continue;
        #pragma unroll
        for (int o = 0; o < 4; ++o) {
            int oc = oc0 + o * 16 + s * 4;
            if constexpr (F32OUT) {
                int m = (gy - 3) * MAP_W + (gx - 3);
                float* op = (float*)out + (size_t)m * 48 + oc;
                #pragma unroll
                for (int r = 0; r < 4; ++r)
                    if (oc + r < 48) op[r] = acc[yy][o][r];
            } else {
                short* op = (short*)out + ((size_t)gy * PW + gx) * OCS + oc;
                unsigned int w0 = f2bf(acc[yy][o][0]) | ((unsigned int)f2bf(acc[yy][o][1]) << 16);
                unsigned int w1 = f2bf(acc[yy][o][2]) | ((unsigned int)f2bf(acc[yy][o][3]) << 16);
                *(uint2*)op = make_uint2(w0, w1);
            }
        }
    }
}

// ===================== conv5 (1x1) + bias, fused bn4(from sums)+relu =====================

__global__ __launch_bounds__(256) void k_conv5(const float* __restrict__ x4, // [M][48]
                                               const float* __restrict__ w,
                                               const float* __restrict__ bias,
                                               const float* __restrict__ sums4,
                                               const float* __restrict__ sums24,
                                               const float* __restrict__ g4,
                                               const float* __restrict__ b4,
                                               float* __restrict__ sem) {
    __shared__ float wl[N_CLS * 48];
    __shared__ float scl[48], shf[48], bl[N_CLS];
    int tid = threadIdx.x;
    for (int e = tid; e < N_CLS * 48; e += 256) wl[e] = w[e];
    if (tid < 48) {
        float mu  = sums4[tid] * (1.f / M_CELLS);
        float var = sums24[tid] * (1.f / M_CELLS) - mu * mu;
        float rs  = rsqrtf(var + 1e-5f);
        scl[tid] = g4[tid] * rs;
        shf[tid] = b4[tid] - mu * rs * g4[tid];
    }
    if (tid < N_CLS) bl[tid] = bias[tid];
    __syncthreads();
    int p = blockIdx.x * 256 + tid;
    if (p >= M_CELLS) return;
    float inr[48];
    const float4* xp = (const float4*)(x4 + (size_t)p * 48);
    #pragma unroll
    for (int q = 0; q < 12; ++q) {
        float4 v = xp[q];
        inr[4*q+0] = v.x; inr[4*q+1] = v.y; inr[4*q+2] = v.z; inr[4*q+3] = v.w;
    }
    #pragma unroll
    for (int c = 0; c < 48; ++c)
        inr[c] = fmaxf(fmaf(inr[c], scl[c], shf[c]), 0.f);
    #pragma unroll
    for (int o = 0; o < N_CLS; ++o) {
        float a = bl[o];
        #pragma unroll
        for (int c = 0; c < 48; ++c) a = fmaf(inr[c], wl[o * 48 + c], a);
        sem[(size_t)o * M_CELLS + p] = a;
    }
}

// ===================== host launcher =====================

extern "C" void kernel_launch(void* const* d_in, const int* in_sizes, int n_in,
                              void* d_out, int out_size, void* d_ws, size_t ws_size,
                              hipStream_t stream) {
    (void)in_sizes; (void)n_in; (void)out_size; (void)ws_size;

    const float* features = (const float*)d_in[0];
    const int*   proj     = (const int*)d_in[1];
    const int*   mask     = (const int*)d_in[2];
    const float* heights  = (const float*)d_in[3];
    const float* w_ih  = (const float*)d_in[6];
    const float* w_hh  = (const float*)d_in[7];
    const float* b_ih  = (const float*)d_in[8];
    const float* b_hh  = (const float*)d_in[9];
    const float* c1_w  = (const float*)d_in[10];
    const float* bn1_g = (const float*)d_in[11];
    const float* bn1_b = (const float*)d_in[12];
    const float* c2_w  = (const float*)d_in[13];
    const float* bn2_g = (const float*)d_in[14];
    const float* bn2_b = (const float*)d_in[15];
    const float* c3_w  = (const float*)d_in[16];
    const float* bn3_g = (const float*)d_in[17];
    const float* bn3_b = (const float*)d_in[18];
    const float* c4_w  = (const float*)d_in[19];
    const float* bn4_g = (const float*)d_in[20];
    const float* bn4_b = (const float*)d_in[21];
    const float* c5_w  = (const float*)d_in[22];
    const float* c5_b  = (const float*)d_in[23];

    // ---- workspace layout; [state|packed|count|sums|sums2] is one zero region ----
    char* ws = (char*)d_ws;
    float* state = (float*)(ws);                                   // 64.0 MB
    unsigned long long* packed = (unsigned long long*)(ws + 64000000); // 5.0 MB [T][M]
    int*   count   = (int*)(ws + 69000000);                        // 64 B [T]
    float* sums    = (float*)(ws + 69000064);                      // 512 f
    float* sums2   = (float*)(ws + 69002112);                      // 512 f
    int*   ps      = (int*)(ws + 70000000);                        // 12.3 MB [T][P]
    int*   updlist = (int*)(ws + 83000000);                        //  2.5 MB [T][NPAD]
    short* Agx     = (short*)(ws + 86000000);                      // 80.0 MB [T][NPAD][64]
    short* wq      = (short*)(ws + 167000000);                     // 0.66 MB
    short* wm1     = (short*)(ws + 168000000);                     // 3.2 MB
    short* wm2     = (short*)(ws + 171300000);
    short* wm3     = (short*)(ws + 171500000);
    short* wm4     = (short*)(ws + 171600000);
    short* x1_cl   = (short*)(ws + 172000000);                     // 18.2 MB
    short* x2_cl   = (short*)(ws + 191000000);                     //  9.1 MB
    short* x3_cl   = (short*)(ws + 201000000);                     //  9.1 MB
    float* x4      = (float*)(ws + 211000000);                     // 12.0 MB

    // one zero-memset: state + packed + count + sums + sums2
    hipMemsetAsync(ws, 0, 69004160, stream);

    // all weight pre-transforms in one dispatch
    k_wprep_all<<<dim3(784, 5), 256, 0, stream>>>(w_ih, w_hh, wq,
                                                  c1_w, wm1, c2_w, wm2,
                                                  c3_w, wm3, c4_w, wm4);

    const int PB = P_PIX / 256;                  // 1200
    const int MB = (M_CELLS + 255) / 256;        // 245
    const int CB = NPAD / 64;                    // 977

    // frame-parallel scan
    k_scatter_all<<<dim3(PB, T_FRAMES), 256, 0, stream>>>(
        (const int2*)proj, mask, heights, packed, ps);
    k_sched<<<MB, 256, 0, stream>>>(packed, updlist, ps, count, (float*)d_out);
    k_gx_all<<<dim3(PB, T_FRAMES), 256, 0, stream>>>(features, ps, Agx);

    // sequential GRU chain (one kernel per frame)
    for (int t = 0; t < T_FRAMES; ++t) {
        k_grumm4<<<CB, 256, 0, stream>>>(Agx + (size_t)t * NPAD * 64, wq,
                                         b_ih, b_hh,
                                         updlist + t * NPAD, count + t, state);
    }

    // conv1 7x7 256->128: TLY=4 (2 blocks/CU), fp32 state input, stats out
    k_cmfma<256, 7, 4, false, true, false, true><<<dim3(16, 16, 2), 256, 0, stream>>>(
        state, wm1, 128, x1_cl, 128,
        nullptr, nullptr, nullptr, nullptr, 0, sums + 0, sums2 + 0);

    // conv2 3x3 128->64 (bn1 from sums fused in; stats out)
    k_cmfma<128, 3, 4, true, true, false, false><<<dim3(16, 16, 1), 256, 0, stream>>>(
        x1_cl, wm2, 64, x2_cl, 64,
        sums + 0, sums2 + 0, bn1_g, bn1_b, 128, sums + 128, sums2 + 128);

    // conv3 3x3 64->48 (bn2 in; stats out)
    k_cmfma<64, 3, 4, true, true, false, false><<<dim3(16, 16, 1), 256, 0, stream>>>(
        x2_cl, wm3, 64, x3_cl, 64,
        sums + 128, sums2 + 128, bn2_g, bn2_b, 64, sums + 192, sums2 + 192);

    // conv4 3x3 48->48 (bn3 in; stats out) -> compact f32 [M][48]
    k_cmfma<64, 3, 4, true, true, true, false><<<dim3(16, 16, 1), 256, 0, stream>>>(
        x3_cl, wm4, 64, x4, 48,
        sums + 192, sums2 + 192, bn3_g, bn3_b, 48, sums + 256, sums2 + 256);

    // conv5 1x1 48->20 + bias (bn4 from sums fused) -> sem
    k_conv5<<<MB, 256, 0, stream>>>(x4, c5_w, c5_b,
                                    sums + 256, sums2 + 256, bn4_g, bn4_b,
                                    (float*)d_out);
}

// Round 15
// 1209.281 us; speedup vs baseline: 2.1381x; 1.0079x over previous
//
#include <hip/hip_runtime.h>
#include <math.h>

// ---------------- problem dims (fixed by setup_inputs) ----------------
#define T_FRAMES 10
#define C_FEAT   64
#define IMG_H    480
#define IMG_W    640
#define P_PIX    (IMG_H*IMG_W)     // 307200
#define MAP_H    250
#define MAP_W    250
#define M_CELLS  (MAP_H*MAP_W)     // 62500
#define D_MEM    256
#define N_CLS    20
#define NPAD     62528             // M_CELLS padded to 64

// padded channels-last plane geometry for bf16 activations: interior origin (3,3)
#define PW  272
#define PH  262
#define PP  (PH*PW)                // 71264 px per padded plane

typedef __attribute__((ext_vector_type(8))) short s16x8;   // 8 bf16 (4 VGPR)
typedef __attribute__((ext_vector_type(4))) float f32x4;   // MFMA acc

__device__ __forceinline__ unsigned short f2bf(float f) {
    unsigned int u = __float_as_uint(f);
    u += 0x7fffu + ((u >> 16) & 1u);      // RNE
    return (unsigned short)(u >> 16);
}
__device__ __forceinline__ float bf2f(unsigned short b) {
    return __uint_as_float(((unsigned int)b) << 16);
}
__device__ __forceinline__ uint4 pack8u(float4 a, float4 b) {
    uint4 r;
    r.x = (unsigned int)f2bf(a.x) | ((unsigned int)f2bf(a.y) << 16);
    r.y = (unsigned int)f2bf(a.z) | ((unsigned int)f2bf(a.w) << 16);
    r.z = (unsigned int)f2bf(b.x) | ((unsigned int)f2bf(b.y) << 16);
    r.w = (unsigned int)f2bf(b.z) | ((unsigned int)f2bf(b.w) << 16);
    return r;
}

// ===================== scan phase (frame-parallel) =====================
// packed[t][m] = max over frame-t inlier pixels of (height_bits<<32 | pixel).
// u64 atomicMax = lexicographic (max height, then max pixel) == reference tie rule.
// Pre-check read skips guaranteed-loser atomics (~45% of them; running-max stats):
// result is bit-identical (stale read only causes a redundant atomic).

__global__ __launch_bounds__(256) void k_scatter_all(const int2* __restrict__ proj,
                                                     const int* __restrict__ mask,
                                                     const float* __restrict__ heights,
                                                     unsigned long long* __restrict__ packed,
                                                     int* __restrict__ ps) {
    int t = blockIdx.y;
    int p = blockIdx.x * 256 + threadIdx.x;           // grid.x*256 == P_PIX exactly
    size_t gp = (size_t)t * P_PIX + p;
    ps[gp] = -1;                                      // init inverse map in-kernel
    if (mask[gp]) return;                             // outlier: never wins
    int2 pr = proj[gp];
    int idx = MAP_W * pr.y + pr.x;
    float mh = heights[gp] + 1000.0f;                 // > 0 -> uint order == float order
    unsigned long long pk = ((unsigned long long)__float_as_uint(mh) << 32)
                            | (unsigned int)p;
    unsigned long long* dst = packed + (size_t)t * M_CELLS + idx;
    if (pk > *dst)                                    // pre-check: skip sure losers
        atomicMax(dst, pk);
}

// k_sched: per cell, walk the 10 frame-maxima in registers; emit per-frame
// updlists/slots/winner-pixel map, plus final hmap/observed direct to d_out.

__global__ __launch_bounds__(256) void k_sched(const unsigned long long* __restrict__ packed,
                                               int* __restrict__ updlist,   // [T][NPAD]
                                               int* __restrict__ ps,        // [T][P_PIX]
                                               int* __restrict__ count,     // [T]
                                               float* __restrict__ out) {
    int m = blockIdx.x * 256 + threadIdx.x;
    if (m >= M_CELLS) return;
    unsigned int pv = 0;                               // == 0.0f (hmap init)
    bool any = false;
    #pragma unroll
    for (int t = 0; t < T_FRAMES; ++t) {
        unsigned long long pk = packed[(size_t)t * M_CELLS + m];
        unsigned int hb = (unsigned int)(pk >> 32);
        if (hb > pv) {                                 // strict: matches new_hmap > hmap
            int slot = atomicAdd(count + t, 1);
            updlist[t * NPAD + slot] = m;
            ps[(size_t)t * P_PIX + (pk & 0xffffffffu)] = slot;
            pv = hb;
            any = true;
        }
    }
    out[(size_t)N_CLS * M_CELLS + m] = any ? 1.0f : 0.0f;
    out[(size_t)N_CLS * M_CELLS + M_CELLS + m] = __uint_as_float(pv);
}

// k_gx_all: ALL frames' winner-pixel feature gather, pixel-order (coalesced).

__global__ __launch_bounds__(256) void k_gx_all(const float* __restrict__ feat_all,
                                                const int* __restrict__ ps,
                                                short* __restrict__ Agx) {
    int t = blockIdx.y;
    int p = blockIdx.x * 256 + threadIdx.x;
    int i = ps[(size_t)t * P_PIX + p];
    if (i < 0) return;
    const float* feat = feat_all + (size_t)t * C_FEAT * P_PIX;
    short* dst = Agx + ((size_t)t * NPAD + i) * 64;
    #pragma unroll
    for (int c8 = 0; c8 < 8; ++c8) {
        unsigned int pk[4];
        #pragma unroll
        for (int q = 0; q < 4; ++q) {
            float f0 = feat[(size_t)(c8 * 8 + 2 * q)     * P_PIX + p];
            float f1 = feat[(size_t)(c8 * 8 + 2 * q + 1) * P_PIX + p];
            pk[q] = (unsigned int)f2bf(f0) | ((unsigned int)f2bf(f1) << 16);
        }
        *(uint4*)(dst + c8 * 8) = make_uint4(pk[0], pk[1], pk[2], pk[3]);
    }
}

// ===================== weight pre-transforms (one dispatch) =====================

__device__ __forceinline__ void wprep_gru_item(int idx,
        const float* __restrict__ w_ih, const float* __restrict__ w_hh,
        short* __restrict__ wq) {
    int gp = idx & 1023, k8 = idx >> 10;
    int tau = gp >> 8, gl = gp & 255;
    unsigned int pk[4];
    #pragma unroll
    for (int q = 0; q < 4; ++q) {
        unsigned int h2[2];
        #pragma unroll
        for (int e = 0; e < 2; ++e) {
            int k = k8 * 8 + q * 2 + e;
            float v = 0.f;
            if (tau == 0)      v = (k < 64) ? w_ih[(size_t)gl * 64 + k]
                                            : w_hh[(size_t)gl * 256 + (k - 64)];
            else if (tau == 1) v = (k < 64) ? w_ih[(size_t)(256 + gl) * 64 + k]
                                            : w_hh[(size_t)(256 + gl) * 256 + (k - 64)];
            else if (tau == 2) v = (k < 64) ? w_ih[(size_t)(512 + gl) * 64 + k] : 0.f;
            else               v = (k < 64) ? 0.f
                                            : w_hh[(size_t)(512 + gl) * 256 + (k - 64)];
            h2[e] = f2bf(v);
        }
        pk[q] = h2[0] | (h2[1] << 16);
    }
    *(uint4*)(wq + (size_t)idx * 8) = make_uint4(pk[0], pk[1], pk[2], pk[3]);
}

__device__ __forceinline__ void wprep_conv_item(int idx, const float* __restrict__ w,
        short* __restrict__ wm, int OC, int CIN, int OCP, int CINP, int KS) {
    int oc  = idx % OCP;
    int t2  = idx / OCP;
    int ci8 = t2 % (CINP / 8);
    int tap = t2 / (CINP / 8);
    unsigned int pk[4];
    #pragma unroll
    for (int q = 0; q < 4; ++q) {
        unsigned int h[2];
        #pragma unroll
        for (int e = 0; e < 2; ++e) {
            int ci = ci8 * 8 + 2*q + e;
            float v = (oc < OC && ci < CIN)
                ? w[((size_t)oc * CIN + ci) * KS * KS + tap] : 0.f;
            h[e] = f2bf(v);
        }
        pk[q] = h[0] | (h[1] << 16);
    }
    *(uint4*)(wm + (size_t)idx * 8) = make_uint4(pk[0], pk[1], pk[2], pk[3]);
}

__global__ __launch_bounds__(256) void k_wprep_all(
        const float* __restrict__ w_ih, const float* __restrict__ w_hh,
        short* __restrict__ wq,
        const float* __restrict__ c1_w, short* __restrict__ wm1,
        const float* __restrict__ c2_w, short* __restrict__ wm2,
        const float* __restrict__ c3_w, short* __restrict__ wm3,
        const float* __restrict__ c4_w, short* __restrict__ wm4) {
    int idx = blockIdx.x * 256 + threadIdx.x;
    switch (blockIdx.y) {
    case 0: if (idx < 40 * 1024)    wprep_gru_item(idx, w_ih, w_hh, wq); break;
    case 1: if (idx < 49*32*128)    wprep_conv_item(idx, c1_w, wm1, 128, 256, 128, 256, 7); break;
    case 2: if (idx < 9*16*64)      wprep_conv_item(idx, c2_w, wm2,  64, 128,  64, 128, 3); break;
    case 3: if (idx < 9*8*64)       wprep_conv_item(idx, c3_w, wm3,  48,  64,  64,  64, 3); break;
    default: if (idx < 9*8*64)      wprep_conv_item(idx, c4_w, wm4,  48,  48,  64,  64, 3); break;
    }
}

// ===================== GRU GEMM v5 (x-part in registers, 32KB LDS) ================
// Block = 64 cells, 256 thr = 4 waves. h-part B (64 cells x 256 k bf16) staged ONCE
// in XOR-swizzled LDS (32KB); x-part B-frags preloaded per-lane from L2-resident
// Agx (lane (u,s) holds cells {16cf+u}, 2 chunks each = 32 VGPR). Wave w handles
// gate groups g16 in {w, w+4, w+8, w+12}; per (g16, ck): 3 A-loads (zero-tau rows
// skipped -> bit-identical), 12 MFMA -> A-reuse 4x.

__global__ __launch_bounds__(256) void k_grumm5(
        const short* __restrict__ Agx_t,
        const short* __restrict__ wq,
        const float* __restrict__ b_ih, const float* __restrict__ b_hh,
        const int* __restrict__ updlist_t, const int* __restrict__ count_t,
        float* __restrict__ state) {
    int n = *count_t;
    int base = blockIdx.x * 64;
    if (base >= n) return;

    __shared__ alignas(16) char B[64 * 512];    // h-part: [cell][256 bf16], swizzled
    __shared__ int ml[64];
    const int tid = threadIdx.x;
    if (tid < 64) {
        int i = base + tid; if (i > n - 1) i = n - 1;   // tail clamp (no write later)
        ml[tid] = updlist_t[i];
    }
    __syncthreads();

    const int w = tid >> 6, l = tid & 63, u = l & 15, s = l >> 4;

    // x-part B-frags in regs: lane (u,s) -> cells 16cf+u, k = ck*32 + 8s
    s16x8 xr[4][2];
    #pragma unroll
    for (int cf = 0; cf < 4; ++cf) {
        const short* ax = Agx_t + ((size_t)(base + 16 * cf + u)) * 64 + 8 * s;
        xr[cf][0] = *(const s16x8*)(ax);
        xr[cf][1] = *(const s16x8*)(ax + 32);
    }

    // stage h-part (k 64..319) from fp32 state, convert: 2048 x 16B
    for (int e = tid; e < 2048; e += 256) {
        int cell = e >> 5, kc = e & 31;
        const float* sp = state + (size_t)ml[cell] * D_MEM + kc * 8;
        float4 v0 = *(const float4*)sp;
        float4 v1 = *(const float4*)(sp + 4);
        int dst = (cell * 512 + kc * 16) ^ ((cell & 7) << 4);
        *(uint4*)(B + dst) = pack8u(v0, v1);
    }
    __syncthreads();

    #pragma unroll 1
    for (int g16 = w; g16 < 16; g16 += 4) {
        f32x4 aR[4], aZ[4], aI[4], aH[4];
        #pragma unroll
        for (int cf = 0; cf < 4; ++cf) {
            aR[cf] = (f32x4){0.f,0.f,0.f,0.f}; aZ[cf] = (f32x4){0.f,0.f,0.f,0.f};
            aI[cf] = (f32x4){0.f,0.f,0.f,0.f}; aH[cf] = (f32x4){0.f,0.f,0.f,0.f};
        }

        // ck 0-1: x-part (r, z, inn) from registers
        #pragma unroll
        for (int ck = 0; ck < 2; ++ck) {
            const short* wr = wq + ((size_t)(ck * 4 + s) * 1024 + g16 * 16 + u) * 8;
            s16x8 ar = *(const s16x8*)(wr);
            s16x8 az = *(const s16x8*)(wr + 256 * 8);
            s16x8 an = *(const s16x8*)(wr + 512 * 8);
            #pragma unroll
            for (int cf = 0; cf < 4; ++cf) {
                aR[cf] = __builtin_amdgcn_mfma_f32_16x16x32_bf16(ar, xr[cf][ck], aR[cf], 0, 0, 0);
                aZ[cf] = __builtin_amdgcn_mfma_f32_16x16x32_bf16(az, xr[cf][ck], aZ[cf], 0, 0, 0);
                aI[cf] = __builtin_amdgcn_mfma_f32_16x16x32_bf16(an, xr[cf][ck], aI[cf], 0, 0, 0);
            }
        }
        // ck 2-9: h-part (r, z, hn) from LDS
        #pragma unroll 2
        for (int ck = 2; ck < 10; ++ck) {
            s16x8 b[4];
            #pragma unroll
            for (int cf = 0; cf < 4; ++cf) {
                int cell = 16 * cf + u;
                int byte = (cell * 512 + (ck - 2) * 64 + s * 16) ^ ((cell & 7) << 4);
                b[cf] = *(const s16x8*)(B + byte);
            }
            const short* wr = wq + ((size_t)(ck * 4 + s) * 1024 + g16 * 16 + u) * 8;
            s16x8 ar = *(const s16x8*)(wr);
            s16x8 az = *(const s16x8*)(wr + 256 * 8);
            s16x8 an = *(const s16x8*)(wr + 768 * 8);
            #pragma unroll
            for (int cf = 0; cf < 4; ++cf) {
                aR[cf] = __builtin_amdgcn_mfma_f32_16x16x32_bf16(ar, b[cf], aR[cf], 0, 0, 0);
                aZ[cf] = __builtin_amdgcn_mfma_f32_16x16x32_bf16(az, b[cf], aZ[cf], 0, 0, 0);
                aH[cf] = __builtin_amdgcn_mfma_f32_16x16x32_bf16(an, b[cf], aH[cf], 0, 0, 0);
            }
        }

        // epilogue: d = g16*16 + 4s + r, cells 16cf+u
        const int d0 = g16 * 16 + 4 * s;
        float bi0[4], bh0[4], bi1[4], bh1[4], bi2[4], bh2[4];
        #pragma unroll
        for (int r = 0; r < 4; ++r) {
            int d = d0 + r;
            bi0[r] = b_ih[d];        bh0[r] = b_hh[d];
            bi1[r] = b_ih[256 + d];  bh1[r] = b_hh[256 + d];
            bi2[r] = b_ih[512 + d];  bh2[r] = b_hh[512 + d];
        }
        #pragma unroll
        for (int cf = 0; cf < 4; ++cf) {
            if (base + 16 * cf + u < n) {
                float* sp = state + (size_t)ml[16 * cf + u] * D_MEM;
                float4 h = *(const float4*)(sp + d0);
                float hv[4] = {h.x, h.y, h.z, h.w};
                float ov[4];
                #pragma unroll
                for (int r = 0; r < 4; ++r) {
                    float rr = aR[cf][r] + bi0[r] + bh0[r];
                    float zz = aZ[cf][r] + bi1[r] + bh1[r];
                    float ii = aI[cf][r] + bi2[r];
                    float hh = aH[cf][r] + bh2[r];
                    float rv = 1.f / (1.f + expf(-rr));
                    float zv = 1.f / (1.f + expf(-zz));
                    float nv = tanhf(ii + rv * hh);
                    ov[r] = (1.f - zv) * nv + zv * hv[r];
                }
                *(float4*)(sp + d0) = make_float4(ov[0], ov[1], ov[2], ov[3]);
            }
        }
    }
}

// ===================== MFMA implicit-GEMM conv, fully fused BN =====================
// TLY = output rows per wave (block = 16 x 4*TLY px). F32IN: read fp32 state
// directly (convert in staging). NORM: apply prev-layer relu(bn(x)) during
// staging; interior mask keeps pads 0. STATS: BN sums from f32 accumulators.

template<int CINP, int KS, int TLY, bool NORM, bool STATS, bool F32OUT, bool F32IN>
__global__ __launch_bounds__(256) void k_cmfma(const void* __restrict__ in,
                                               const short* __restrict__ wm,
                                               int OCT,
                                               void* __restrict__ out,
                                               int OCS,
                                               const float* __restrict__ sums_in,
                                               const float* __restrict__ sums2_in,
                                               const float* __restrict__ g_in,
                                               const float* __restrict__ b_in,
                                               int OCPREV,
                                               float* __restrict__ sums_out,
                                               float* __restrict__ sums2_out) {
    constexpr int PAD = KS / 2;
    constexpr int BH  = 4 * TLY;
    constexpr int PTW_X = 16 + KS - 1;
    constexpr int PTW_Y = BH + KS - 1;
    __shared__ alignas(16) char patch[PTW_Y * PTW_X * 64];
    __shared__ float scl[NORM ? CINP : 1], shf[NORM ? CINP : 1];
    __shared__ float st1[4][64], st2[4][64];

    const int tid = threadIdx.x;
    const int w   = tid >> 6;
    const int l   = tid & 63;
    const int u   = l & 15;
    const int s   = l >> 4;

    const int x0  = 3 + 16 * blockIdx.x;
    const int y0  = 3 + BH * blockIdx.y;
    const int oc0 = 64 * blockIdx.z;

    if constexpr (NORM) {
        for (int c = tid; c < CINP; c += 256) {
            float sc = 0.f, sh = 0.f;
            if (c < OCPREV) {
                float mu  = sums_in[c] * (1.f / M_CELLS);
                float var = sums2_in[c] * (1.f / M_CELLS) - mu * mu;
                float rs  = rsqrtf(var + 1e-5f);
                sc = g_in[c] * rs;
                sh = b_in[c] - mu * rs * g_in[c];
            }
            scl[c] = sc; shf[c] = sh;
        }
    }

    f32x4 acc[TLY][4];   // [yy][o]
    #pragma unroll
    for (int yy = 0; yy < TLY; ++yy)
        #pragma unroll
        for (int o = 0; o < 4; ++o)
            acc[yy][o] = (f32x4){0.f, 0.f, 0.f, 0.f};

    for (int ci0 = 0; ci0 < CINP; ci0 += 32) {
        __syncthreads();
        for (int e = tid; e < PTW_Y * PTW_X * 4; e += 256) {
            int c8 = e & 3;
            int pp = e >> 2;
            int px = pp % PTW_X, py = pp / PTW_X;
            int gy = y0 - PAD + py, gx = x0 - PAD + px;
            bool inb = (gy >= 3) && (gy < 253) && (gx >= 3) && (gx < 253);
            uint4 v = make_uint4(0, 0, 0, 0);
            if constexpr (F32IN) {
                if (inb) {
                    int m = (gy - 3) * MAP_W + (gx - 3);
                    const float* sp = (const float*)in + (size_t)m * 256 + ci0 + c8 * 8;
                    float4 v0 = *(const float4*)sp;
                    float4 v1 = *(const float4*)(sp + 4);
                    v = pack8u(v0, v1);
                }
            } else {
                v = *(const uint4*)((const short*)in + ((size_t)gy * PW + gx) * CINP
                                    + ci0 + c8 * 8);
                if constexpr (NORM) {
                    int cb = ci0 + c8 * 8;
                    unsigned int uu[4] = {v.x, v.y, v.z, v.w};
                    unsigned int ro[4];
                    #pragma unroll
                    for (int q = 0; q < 4; ++q) {
                        float f0 = bf2f((unsigned short)(uu[q] & 0xffffu));
                        float f1 = bf2f((unsigned short)(uu[q] >> 16));
                        f0 = fmaxf(fmaf(f0, scl[cb + 2*q],     shf[cb + 2*q]),     0.f);
                        f1 = fmaxf(fmaf(f1, scl[cb + 2*q + 1], shf[cb + 2*q + 1]), 0.f);
                        ro[q] = (unsigned int)f2bf(f0) | ((unsigned int)f2bf(f1) << 16);
                    }
                    v = make_uint4(ro[0], ro[1], ro[2], ro[3]);
                }
                if (!inb) v = make_uint4(0, 0, 0, 0);
            }
            int lb = (((py * PTW_X + px) * 64) + c8 * 16) ^ ((px & 3) << 4);
            *(uint4*)(patch + lb) = v;
        }
        __syncthreads();

        const short* wb = wm + ((size_t)(ci0 / 8 + s) * OCT + oc0 + u) * 8;

        for (int ky = 0; ky < KS; ++ky) {
            for (int kx = 0; kx < KS; ++kx) {
                const int tap = ky * KS + kx;
                const short* wt = wb + (size_t)tap * (CINP / 8) * OCT * 8;
                s16x8 a[4];
                #pragma unroll
                for (int o = 0; o < 4; ++o)
                    a[o] = *(const s16x8*)(wt + o * 16 * 8);
                const int px = kx + u;
                const int lb0 = ((px * 64) + s * 16) ^ ((px & 3) << 4);
                #pragma unroll
                for (int yy = 0; yy < TLY; ++yy) {
                    int py = TLY * w + yy + ky;
                    s16x8 b = *(const s16x8*)(patch + py * PTW_X * 64 + lb0);
                    #pragma unroll
                    for (int o = 0; o < 4; ++o)
                        acc[yy][o] = __builtin_amdgcn_mfma_f32_16x16x32_bf16(
                            a[o], b, acc[yy][o], 0, 0, 0);
                }
            }
        }
    }

    const int gx = x0 + u;
    const bool colok = (gx < 253);

    if constexpr (STATS) {
        float s1[16], s2[16];
        #pragma unroll
        for (int e = 0; e < 16; ++e) { s1[e] = 0.f; s2[e] = 0.f; }
        #pragma unroll
        for (int yy = 0; yy < TLY; ++yy) {
            int gy = y0 + TLY * w + yy;
            if (colok && gy < 253) {
                #pragma unroll
                for (int o = 0; o < 4; ++o)
                    #pragma unroll
                    for (int r = 0; r < 4; ++r) {
                        float v = acc[yy][o][r];
                        s1[o*4+r] += v; s2[o*4+r] += v * v;
                    }
            }
        }
        #pragma unroll
        for (int off = 1; off < 16; off <<= 1)
            #pragma unroll
            for (int e = 0; e < 16; ++e) {
                s1[e] += __shfl_xor(s1[e], off, 64);
                s2[e] += __shfl_xor(s2[e], off, 64);
            }
        if (u == 0) {
            #pragma unroll
            for (int e = 0; e < 16; ++e) {
                int ch = (e >> 2) * 16 + s * 4 + (e & 3);
                st1[w][ch] = s1[e]; st2[w][ch] = s2[e];
            }
        }
        __syncthreads();
        if (tid < 64) {
            float a1 = st1[0][tid] + st1[1][tid] + st1[2][tid] + st1[3][tid];
            float a2 = st2[0][tid] + st2[1][tid] + st2[2][tid] + st2[3][tid];
            atomicAdd(sums_out  + oc0 + tid, a1);
            atomicAdd(sums2_out + oc0 + tid, a2);
        }
    }

    if (!colok) return;
    #pragma unroll
    for (int yy = 0; yy < TLY; ++yy) {
        int gy = y0 + TLY * w + yy;
        if (gy >= 253) continue;
        #pragma unroll
        for (int o = 0; o < 4; ++o) {
            int oc = oc0 + o * 16 + s * 4;
            if constexpr (F32OUT) {
                int m = (gy - 3) * MAP_W + (gx - 3);
                float* op = (float*)out + (size_t)m * 48 + oc;
                #pragma unroll
                for (int r = 0; r < 4; ++r)
                    if (oc + r < 48) op[r] = acc[yy][o][r];
            } else {
                short* op = (short*)out + ((size_t)gy * PW + gx) * OCS + oc;
                unsigned int w0 = f2bf(acc[yy][o][0]) | ((unsigned int)f2bf(acc[yy][o][1]) << 16);
                unsigned int w1 = f2bf(acc[yy][o][2]) | ((unsigned int)f2bf(acc[yy][o][3]) << 16);
                *(uint2*)op = make_uint2(w0, w1);
            }
        }
    }
}

// ===================== conv5 (1x1) + bias, fused bn4(from sums)+relu =====================

__global__ __launch_bounds__(256) void k_conv5(const float* __restrict__ x4, // [M][48]
                                               const float* __restrict__ w,
                                               const float* __restrict__ bias,
                                               const float* __restrict__ sums4,
                                               const float* __restrict__ sums24,
                                               const float* __restrict__ g4,
                                               const float* __restrict__ b4,
                                               float* __restrict__ sem) {
    __shared__ float wl[N_CLS * 48];
    __shared__ float scl[48], shf[48], bl[N_CLS];
    int tid = threadIdx.x;
    for (int e = tid; e < N_CLS * 48; e += 256) wl[e] = w[e];
    if (tid < 48) {
        float mu  = sums4[tid] * (1.f / M_CELLS);
        float var = sums24[tid] * (1.f / M_CELLS) - mu * mu;
        float rs  = rsqrtf(var + 1e-5f);
        scl[tid] = g4[tid] * rs;
        shf[tid] = b4[tid] - mu * rs * g4[tid];
    }
    if (tid < N_CLS) bl[tid] = bias[tid];
    __syncthreads();
    int p = blockIdx.x * 256 + tid;
    if (p >= M_CELLS) return;
    float inr[48];
    const float4* xp = (const float4*)(x4 + (size_t)p * 48);
    #pragma unroll
    for (int q = 0; q < 12; ++q) {
        float4 v = xp[q];
        inr[4*q+0] = v.x; inr[4*q+1] = v.y; inr[4*q+2] = v.z; inr[4*q+3] = v.w;
    }
    #pragma unroll
    for (int c = 0; c < 48; ++c)
        inr[c] = fmaxf(fmaf(inr[c], scl[c], shf[c]), 0.f);
    #pragma unroll
    for (int o = 0; o < N_CLS; ++o) {
        float a = bl[o];
        #pragma unroll
        for (int c = 0; c < 48; ++c) a = fmaf(inr[c], wl[o * 48 + c], a);
        sem[(size_t)o * M_CELLS + p] = a;
    }
}

// ===================== host launcher =====================

extern "C" void kernel_launch(void* const* d_in, const int* in_sizes, int n_in,
                              void* d_out, int out_size, void* d_ws, size_t ws_size,
                              hipStream_t stream) {
    (void)in_sizes; (void)n_in; (void)out_size; (void)ws_size;

    const float* features = (const float*)d_in[0];
    const int*   proj     = (const int*)d_in[1];
    const int*   mask     = (const int*)d_in[2];
    const float* heights  = (const float*)d_in[3];
    const float* w_ih  = (const float*)d_in[6];
    const float* w_hh  = (const float*)d_in[7];
    const float* b_ih  = (const float*)d_in[8];
    const float* b_hh  = (const float*)d_in[9];
    const float* c1_w  = (const float*)d_in[10];
    const float* bn1_g = (const float*)d_in[11];
    const float* bn1_b = (const float*)d_in[12];
    const float* c2_w  = (const float*)d_in[13];
    const float* bn2_g = (const float*)d_in[14];
    const float* bn2_b = (const float*)d_in[15];
    const float* c3_w  = (const float*)d_in[16];
    const float* bn3_g = (const float*)d_in[17];
    const float* bn3_b = (const float*)d_in[18];
    const float* c4_w  = (const float*)d_in[19];
    const float* bn4_g = (const float*)d_in[20];
    const float* bn4_b = (const float*)d_in[21];
    const float* c5_w  = (const float*)d_in[22];
    const float* c5_b  = (const float*)d_in[23];

    // ---- workspace layout; [state|packed|count|sums|sums2] is one zero region ----
    char* ws = (char*)d_ws;
    float* state = (float*)(ws);                                   // 64.0 MB
    unsigned long long* packed = (unsigned long long*)(ws + 64000000); // 5.0 MB [T][M]
    int*   count   = (int*)(ws + 69000000);                        // 64 B [T]
    float* sums    = (float*)(ws + 69000064);                      // 512 f
    float* sums2   = (float*)(ws + 69002112);                      // 512 f
    int*   ps      = (int*)(ws + 70000000);                        // 12.3 MB [T][P]
    int*   updlist = (int*)(ws + 83000000);                        //  2.5 MB [T][NPAD]
    short* Agx     = (short*)(ws + 86000000);                      // 80.0 MB [T][NPAD][64]
    short* wq      = (short*)(ws + 167000000);                     // 0.66 MB
    short* wm1     = (short*)(ws + 168000000);                     // 3.2 MB
    short* wm2     = (short*)(ws + 171300000);
    short* wm3     = (short*)(ws + 171500000);
    short* wm4     = (short*)(ws + 171600000);
    short* x1_cl   = (short*)(ws + 172000000);                     // 18.2 MB
    short* x2_cl   = (short*)(ws + 191000000);                     //  9.1 MB
    short* x3_cl   = (short*)(ws + 201000000);                     //  9.1 MB
    float* x4      = (float*)(ws + 211000000);                     // 12.0 MB

    // one zero-memset: state + packed + count + sums + sums2
    hipMemsetAsync(ws, 0, 69004160, stream);

    // all weight pre-transforms in one dispatch
    k_wprep_all<<<dim3(784, 5), 256, 0, stream>>>(w_ih, w_hh, wq,
                                                  c1_w, wm1, c2_w, wm2,
                                                  c3_w, wm3, c4_w, wm4);

    const int PB = P_PIX / 256;                  // 1200
    const int MB = (M_CELLS + 255) / 256;        // 245
    const int CB = NPAD / 64;                    // 977

    // frame-parallel scan
    k_scatter_all<<<dim3(PB, T_FRAMES), 256, 0, stream>>>(
        (const int2*)proj, mask, heights, packed, ps);
    k_sched<<<MB, 256, 0, stream>>>(packed, updlist, ps, count, (float*)d_out);
    k_gx_all<<<dim3(PB, T_FRAMES), 256, 0, stream>>>(features, ps, Agx);

    // sequential GRU chain (one kernel per frame)
    for (int t = 0; t < T_FRAMES; ++t) {
        k_grumm5<<<CB, 256, 0, stream>>>(Agx + (size_t)t * NPAD * 64, wq,
                                         b_ih, b_hh,
                                         updlist + t * NPAD, count + t, state);
    }

    // conv1 7x7 256->128: TLY=4 (2 blocks/CU), fp32 state input, stats out
    k_cmfma<256, 7, 4, false, true, false, true><<<dim3(16, 16, 2), 256, 0, stream>>>(
        state, wm1, 128, x1_cl, 128,
        nullptr, nullptr, nullptr, nullptr, 0, sums + 0, sums2 + 0);

    // conv2 3x3 128->64 (bn1 from sums fused in; stats out)
    k_cmfma<128, 3, 4, true, true, false, false><<<dim3(16, 16, 1), 256, 0, stream>>>(
        x1_cl, wm2, 64, x2_cl, 64,
        sums + 0, sums2 + 0, bn1_g, bn1_b, 128, sums + 128, sums2 + 128);

    // conv3 3x3 64->48 (bn2 in; stats out)
    k_cmfma<64, 3, 4, true, true, false, false><<<dim3(16, 16, 1), 256, 0, stream>>>(
        x2_cl, wm3, 64, x3_cl, 64,
        sums + 128, sums2 + 128, bn2_g, bn2_b, 64, sums + 192, sums2 + 192);

    // conv4 3x3 48->48 (bn3 in; stats out) -> compact f32 [M][48]
    k_cmfma<64, 3, 4, true, true, true, false><<<dim3(16, 16, 1), 256, 0, stream>>>(
        x3_cl, wm4, 64, x4, 48,
        sums + 192, sums2 + 192, bn3_g, bn3_b, 48, sums + 256, sums2 + 256);

    // conv5 1x1 48->20 + bias (bn4 from sums fused) -> sem
    k_conv5<<<MB, 256, 0, stream>>>(x4, c5_w, c5_b,
                                    sums + 256, sums2 + 256, bn4_g, bn4_b,
                                    (float*)d_out);
}